// Round 17
// baseline (120.463 us; speedup 1.0000x reference)
//
#include <hip/hip_runtime.h>
#include <math.h>

#define B_  8
#define C_  128
#define H_  128
#define W_  128
#define HW_ 16384

// ---- workspace layout (float offsets) ----
#define OFF_MPART 0          // [64 bblk][16 ps][256]     = 262144
#define OFF_SPART 262144     // [4 kind][1024 bc][16 ps]  = 65536
#define OFF_M     327680     // [64 bblk][256]            = 16384
#define OFF_S     344064     // [4 kind][1024 bc]         = 4096
#define OFF_WV    348160     // [8][16][16][16]           = 32768
#define OFF_CST   380928     // [8][256]                  = 2048
#define OFF_T     382976     // [8][128][9]               = 9216
#define OFF_WEFF  392192     // bf16 [8][9 tap][128 oc][128 cin] = 1179648 ushort = 589824 fl
#define OFF_T2F   982016     // bf16 T2 [8][130 y'][130 x'][128 c] = 17305600 ushort
#define T2_ROW    16640      // 130*128 shorts
#define T2_BATCH  2163200    // 130*16640 shorts
#define WS_NEED   (982016ull * 4ull + 34611200ull)

typedef __attribute__((ext_vector_type(8))) short short8;
typedef __attribute__((ext_vector_type(4))) float f32x4;

__device__ __forceinline__ unsigned short f2bf(float f) {
  unsigned u = __float_as_uint(f);
  u += 0x7fffu + ((u >> 16) & 1u);
  return (unsigned short)(u >> 16);
}

__device__ __forceinline__ f32x4 mfma16(short8 a, short8 b, f32x4 c) {
  return __builtin_amdgcn_mfma_f32_16x16x32_bf16(a, b, c, 0, 0, 0);
}

// async global->LDS 16B (CK-style addrspace casts; LDS offset = low 32 bits)
__device__ __forceinline__ void gl16(const void* g, void* l) {
  const unsigned loff = (unsigned)(unsigned long long)l;
  __builtin_amdgcn_global_load_lds(
      (const __attribute__((address_space(1))) void*)g,
      (__attribute__((address_space(3))) void*)loff, 16, 0, 0);
}

// K1 (MFMA Gram): grid = b(8) x blk(8) x ps(16).
__global__ __launch_bounds__(256) void k_gram(const float* __restrict__ x,
                                              const float* __restrict__ to,
                                              float* __restrict__ ws) {
  const int bid = blockIdx.x;       // 0..1023
  const int ps  = bid & 15;
  const int blk = (bid >> 4) & 7;
  const int b   = bid >> 7;
  const int tid = threadIdx.x;
  const int w = tid >> 6, l = tid & 63;
  const int lm = l & 15, lh = l >> 4;
  const int c0 = blk * 16;

  const float* xc = x  + ((size_t)b * C_ + c0 + lm) * HW_;
  const float* tc = to + ((size_t)b * C_ + c0 + lm) * HW_;
  const int p0 = ps * 1024 + w * 256 + lh * 8;

  f32x4 acc = (f32x4)0.f;
  float sx = 0.f, sxx = 0.f, st = 0.f, stt = 0.f;
#pragma unroll
  for (int it = 0; it < 8; ++it) {
    const int p = p0 + it * 32;
    const f32x4 xa = *(const f32x4*)(xc + p);
    const f32x4 xb = *(const f32x4*)(xc + p + 4);
    const f32x4 ta = *(const f32x4*)(tc + p);
    const f32x4 tb = *(const f32x4*)(tc + p + 4);
    short8 xf, tf;
#pragma unroll
    for (int e = 0; e < 4; ++e) {
      xf[e]     = (short)f2bf(xa[e]);
      xf[4 + e] = (short)f2bf(xb[e]);
      tf[e]     = (short)f2bf(ta[e]);
      tf[4 + e] = (short)f2bf(tb[e]);
      sx += xa[e] + xb[e];
      sxx = fmaf(xa[e], xa[e], fmaf(xb[e], xb[e], sxx));
      st += ta[e] + tb[e];
      stt = fmaf(ta[e], ta[e], fmaf(tb[e], tb[e], stt));
    }
    acc = mfma16(xf, tf, acc);   // D[m=x-ch][n=to-ch]
  }

  sx  += __shfl_xor(sx, 16);  sx  += __shfl_xor(sx, 32);
  sxx += __shfl_xor(sxx, 16); sxx += __shfl_xor(sxx, 32);
  st  += __shfl_xor(st, 16);  st  += __shfl_xor(st, 32);
  stt += __shfl_xor(stt, 16); stt += __shfl_xor(stt, 32);

  __shared__ float smM[4][256];
  __shared__ float smS[4][4][16];
#pragma unroll
  for (int r = 0; r < 4; ++r)
    smM[w][(lh * 4 + r) * 16 + lm] = acc[r];   // row=(l>>4)*4+r, col=l&15 (m89)
  if (l < 16) {
    smS[w][0][lm] = sx;  smS[w][1][lm] = sxx;
    smS[w][2][lm] = st;  smS[w][3][lm] = stt;
  }
  __syncthreads();

  {
    const float s = smM[0][tid & 255] + smM[1][tid & 255]
                  + smM[2][tid & 255] + smM[3][tid & 255];
    ws[OFF_MPART + (size_t)((b * 8 + blk) * 16 + ps) * 256 + tid] = s;
  }
  if (tid < 64) {
    const int kind = tid >> 4, ch = tid & 15;
    const float s = smS[0][kind][ch] + smS[1][kind][ch]
                  + smS[2][kind][ch] + smS[3][kind][ch];
    ws[OFF_SPART + (size_t)kind * 16384 + (size_t)(b * C_ + c0 + ch) * 16 + ps] = s;
  }
}

// K1b: parallel reduction of partials (16 ps slices).
__global__ __launch_bounds__(256) void k_redB(float* __restrict__ ws) {
  const int gid = blockIdx.x * 256 + threadIdx.x;   // 80*256 = 20480
  if (gid < 16384) {
    const float* mp = ws + OFF_MPART + (size_t)(gid >> 8) * 4096 + (gid & 255);
    float s = 0.f;
#pragma unroll
    for (int kc = 0; kc < 16; ++kc) s += mp[kc * 256];
    ws[OFF_M + gid] = s;
  } else {
    const int sidx = gid - 16384;
    const float* sp = ws + OFF_SPART + (size_t)sidx * 16;
    float s = 0.f;
#pragma unroll
    for (int kc = 0; kc < 16; ++kc) s += sp[kc];
    ws[OFF_S + sidx] = s;
  }
}

// K_zero: zero T2 rows y'=0 and y'=129 for each batch.
__global__ __launch_bounds__(256) void k_zero(unsigned short* __restrict__ t2) {
  const int b = blockIdx.x >> 1, r = blockIdx.x & 1;
  unsigned short* row = t2 + (size_t)b * T2_BATCH + (size_t)(r ? 129 : 0) * T2_ROW;
  const short8 z = {0,0,0,0,0,0,0,0};
  for (int idx = threadIdx.x; idx < 2080; idx += 256)
    *(short8*)(row + (size_t)idx * 8) = z;
}

// K_tr: transpose to -> bf16 T2[b][y'][x'][c], y'=y+1, x'=x+1. float4 loads.
__global__ __launch_bounds__(256) void k_tr(const float* __restrict__ to,
                                            unsigned short* __restrict__ t2) {
  const int d  = blockIdx.x;          // 2048 = xh(2) * y(128) * b(8)
  const int xh = d & 1;
  const int y  = (d >> 1) & 127;
  const int b  = d >> 8;
  const int tid = threadIdx.x;
  __shared__ char lds[64 * 256];      // 16 KB

  const int x0 = xh * 64;
  const int xq = tid & 15;            // x-quad: x0 + xq*4 .. +3
  const int cg = tid >> 4;            // channel group: cg*8 .. +7
  const float* srcb = to + ((size_t)b * C_ + cg * 8) * HW_ + (size_t)y * W_ + x0 + xq * 4;
#pragma unroll
  for (int k = 0; k < 8; ++k) {
    const f32x4 v = *(const f32x4*)(srcb + (size_t)k * HW_);
    const int c = cg * 8 + k;
#pragma unroll
    for (int e = 0; e < 4; ++e) {
      const int xl = xq * 4 + e;
      const int boff = xl * 256 + ((2 * c) ^ ((xl & 7) << 4));
      *(unsigned short*)(lds + boff) = f2bf(v[e]);
    }
  }
  __syncthreads();

  unsigned short* rowbase = t2 + (size_t)b * T2_BATCH + (size_t)(y + 1) * T2_ROW;
#pragma unroll
  for (int i = 0; i < 4; ++i) {
    const int xx = tid >> 2;
    const int cs = (tid & 3) + i * 4;   // 0..15
    short8 val = *(short8*)(lds + xx * 256 + ((cs * 16) ^ ((xx & 7) << 4)));
    *(short8*)(rowbase + (size_t)(x0 + xx + 1) * 128 + cs * 8) = val;
  }
  if (tid < 16) {
    short8 z = {0,0,0,0,0,0,0,0};
    if (xh == 0) *(short8*)(rowbase + tid * 8) = z;
    else         *(short8*)(rowbase + (size_t)129 * 128 + tid * 8) = z;
  }
}

// K2 (parallel): one block per batch, thread = (h, i).
__global__ __launch_bounds__(256) void k_attn(const float* __restrict__ t,
    const float* __restrict__ w_r1, const float* __restrict__ b_r1,
    const float* __restrict__ w_r2, const float* __restrict__ b_r2,
    const float* __restrict__ w_r3, const float* __restrict__ b_r3,
    const float* __restrict__ w_t1, const float* __restrict__ b_t1,
    const float* __restrict__ w_t2, const float* __restrict__ b_t2,
    const float* __restrict__ w_t3, const float* __restrict__ b_t3,
    float* __restrict__ ws) {
  const int b = blockIdx.x;          // 0..7
  const int tid = threadIdx.x;       // h = tid>>4, i = tid&15
  __shared__ float aQ[256], bQ[256], aK[256], bK[256], aV[256], bV[256];
  __shared__ float rks[256], kAs[256], kBs[256], stos[256];

  if (tid < 128) {
    const int g = tid;
    float A1[4], B1[4], A2[2], B2[2];
#pragma unroll
    for (int j = 0; j < 4; ++j) { A1[j] = w_r1[g * 4 + j]; B1[j] = b_r1[g * 4 + j]; }
#pragma unroll
    for (int i = 0; i < 2; ++i) {
      A2[i] = 0.f; B2[i] = b_r2[g * 2 + i];
#pragma unroll
      for (int j = 0; j < 4; ++j) {
        const float w = w_r2[(g * 2 + i) * 4 + j];
        A2[i] = fmaf(w, A1[j], A2[i]); B2[i] = fmaf(w, B1[j], B2[i]);
      }
    }
#pragma unroll
    for (int o = 0; o < 2; ++o) {
      float a = 0.f, bb = b_r3[g * 2 + o];
#pragma unroll
      for (int i = 0; i < 2; ++i) {
        const float w = w_r3[(g * 2 + o) * 2 + i];
        a = fmaf(w, A2[i], a); bb = fmaf(w, B2[i], bb);
      }
      aQ[g * 2 + o] = a; bQ[g * 2 + o] = bb;
    }
#pragma unroll
    for (int j = 0; j < 4; ++j) { A1[j] = w_t1[g * 4 + j]; B1[j] = b_t1[g * 4 + j]; }
#pragma unroll
    for (int i = 0; i < 2; ++i) {
      A2[i] = 0.f; B2[i] = b_t2[g * 2 + i];
#pragma unroll
      for (int j = 0; j < 4; ++j) {
        const float w = w_t2[(g * 2 + i) * 4 + j];
        A2[i] = fmaf(w, A1[j], A2[i]); B2[i] = fmaf(w, B1[j], B2[i]);
      }
    }
#pragma unroll
    for (int o = 0; o < 4; ++o) {
      float a = 0.f, bb = b_t3[g * 4 + o];
#pragma unroll
      for (int i = 0; i < 2; ++i) {
        const float w = w_t3[(g * 4 + o) * 2 + i];
        a = fmaf(w, A2[i], a); bb = fmaf(w, B2[i], bb);
      }
      if (o < 2) { aK[g * 2 + o] = a; bK[g * 2 + o] = bb; }
      else       { aV[g * 2 + (o - 2)] = a; bV[g * 2 + (o - 2)] = bb; }
    }
  }
  __syncthreads();

  const float* S   = ws + OFF_S;
  const float* Sx  = S;
  const float* Sxx = S + 1024;
  const float* Sto = S + 2048;
  const float* Stt = S + 3072;

  {
    const int h = tid >> 4, e = h >> 3, blk = h & 7, c0 = blk * 16;
    const int g = c0 + (tid & 15);
    const float a = aK[g * 2 + e], bb = bK[g * 2 + e];
    const float s2 = a * a * Stt[b * C_ + g] + 2.f * a * bb * Sto[b * C_ + g]
                   + bb * bb * 16384.f;
    rks[tid] = 1.f / fmaxf(sqrtf(fmaxf(s2, 0.f)), 1e-12f);
    kAs[tid] = a; kBs[tid] = bb;
    stos[tid] = Sto[b * C_ + g];
  }
  __syncthreads();

  {
    const int h = tid >> 4, i = tid & 15, e = h >> 3, blk = h & 7, c0 = blk * 16;
    const int gi = c0 + i;
    const float gA = aQ[gi * 2 + e], gB = bQ[gi * 2 + e];
    const float sxi = Sx[b * C_ + gi];
    const float q2 = gA * gA * Sxx[b * C_ + gi] + 2.f * gA * gB * sxi
                   + gB * gB * 16384.f;
    const float rnq = 1.f / fmaxf(sqrtf(fmaxf(q2, 0.f)), 1e-12f);
    const float tt = t[h];
    const float* Mrow = ws + OFF_M + (size_t)(b * 8 + blk) * 256 + i * 16;

    float lg[16];
    float mx = -1e30f;
#pragma unroll
    for (int j = 0; j < 16; ++j) {
      const float s = gA * kAs[h * 16 + j] * Mrow[j]
                    + gA * kBs[h * 16 + j] * sxi
                    + gB * kAs[h * 16 + j] * stos[h * 16 + j]
                    + gB * kBs[h * 16 + j] * 16384.f;
      const float l = tt * s * rnq * rks[h * 16 + j];
      lg[j] = l;
      mx = fmaxf(mx, l);
    }
    float den = 0.f;
#pragma unroll
    for (int j = 0; j < 16; ++j) { const float ev = expf(lg[j] - mx); lg[j] = ev; den += ev; }
    const float inv = 1.f / den;
    float cs = 0.f;
    float* WVp = ws + OFF_WV + (size_t)(b * 16 + h) * 256 + i * 16;
#pragma unroll
    for (int j = 0; j < 16; ++j) {
      const float aa = lg[j] * inv;
      const int gj = c0 + j;
      WVp[j] = aa * aV[gj * 2 + e];
      cs = fmaf(aa, bV[gj * 2 + e], cs);
    }
    ws[OFF_CST + b * 256 + i * 16 + h] = cs;
  }
}

// K3: fold attention into per-batch bf16 conv weights + constant taps.
__global__ __launch_bounds__(128) void k_weff(const float* __restrict__ w_f,
                                              float* __restrict__ ws) {
  const int b = blockIdx.x >> 7, oc = blockIdx.x & 127;
  const int c = threadIdx.x, blk = c >> 4, j = c & 15;
  const float* WVb = ws + OFF_WV;
  float acc[9];
#pragma unroll
  for (int k = 0; k < 9; ++k) acc[k] = 0.f;
#pragma unroll
  for (int e = 0; e < 2; ++e) {
    const int h = e * 8 + blk;
#pragma unroll
    for (int i = 0; i < 16; ++i) {
      const float coef = WVb[((size_t)(b * 16 + h) * 16 + i) * 16 + j];
      const float* wf = w_f + (size_t)(oc * 256 + i * 16 + h) * 9;
#pragma unroll
      for (int k = 0; k < 9; ++k) acc[k] = fmaf(wf[k], coef, acc[k]);
    }
  }
  unsigned short* wb16 = (unsigned short*)(ws + OFF_WEFF);
#pragma unroll
  for (int k = 0; k < 9; ++k)
    wb16[(((size_t)(b * 9 + k)) * 128 + oc) * 128 + c] = f2bf(acc[k]);

  __shared__ float tp[9][128];
  float tl[9];
#pragma unroll
  for (int k = 0; k < 9; ++k) tl[k] = 0.f;
  const float* cst = ws + OFF_CST + b * 256;
  for (int cc = c; cc < 256; cc += 128) {
    const float cv = cst[cc];
    const float* wf = w_f + (size_t)(oc * 256 + cc) * 9;
#pragma unroll
    for (int k = 0; k < 9; ++k) tl[k] = fmaf(wf[k], cv, tl[k]);
  }
#pragma unroll
  for (int k = 0; k < 9; ++k) tp[k][c] = tl[k];
  __syncthreads();
  for (int s = 64; s > 0; s >>= 1) {
    if (c < s) {
#pragma unroll
      for (int k = 0; k < 9; ++k) tp[k][c] += tp[k][c + s];
    }
    __syncthreads();
  }
  if (c < 9) ws[OFF_T + ((size_t)b * 128 + oc) * 9 + c] = tp[c][0];
}

// K4: BK=32, 4 blocks/CU double-buffered gload_lds conv-GEMM.
// 256 threads, wave tile 64 oc x 64 px, 36 steps (9 taps x 4 cin-quarters).
// LDS: A[2][128][32] + B[2][128][32] bf16 = 32 KiB -> 4 blocks/CU: barrier
// drains of independent blocks interleave (TLP covers the stage tail).
__global__ __launch_bounds__(256, 4) void k_conv(const float* __restrict__ xin,
                                                 const float* __restrict__ b_f,
                                                 const float* __restrict__ ws,
                                                 const unsigned short* __restrict__ t2,
                                                 float* __restrict__ out) {
  const int d = blockIdx.x;           // 1024 = b(8, fast -> XCD) * y(128)
  const int b = d & 7;
  const int y = d >> 3;
  const int tid = threadIdx.x;

  __shared__ unsigned short As[2][128 * 32];
  __shared__ unsigned short Bs[2][128 * 32];

  const unsigned short* wb = (const unsigned short*)(ws + OFF_WEFF)
      + (size_t)b * 9 * 16384;
  const unsigned short* t2y = t2 + (size_t)b * T2_BATCH + (size_t)y * T2_ROW;

  const int l = tid & 63;
  const int lm = l & 15, lh = l >> 4;
  const int wv = tid >> 6;            // 0..3
  const int oc0w = (wv & 1) * 64;     // 2 oc-halves
  const int px0w = (wv >> 1) * 64;    // 2 px-halves

  // staging: 512 tasks per tile (16B each); 256 threads x 2 chunks.
  // task row = task>>2 (64B rows), chunk tci0 = task&3, swizzle ^= row&3.
  const int trow0 = tid >> 2, tci0 = tid & 3;
  const unsigned udstw = (unsigned)((tid & ~63) * 16);

#define STAGE(BUF, S)                                                          \
  {                                                                            \
    const int tap_ = (S) >> 2, ks_ = (S) & 3;                                  \
    const int dy_ = tap_ / 3, dx_ = tap_ - dy_ * 3;                            \
    const unsigned short* asrc = wb + (size_t)tap_ * 16384 + ks_ * 32;         \
    const unsigned short* bsrc = t2y + (size_t)dy_ * T2_ROW + dx_ * 128 + ks_ * 32; \
    _Pragma("unroll")                                                          \
    for (int k_ = 0; k_ < 2; ++k_) {                                           \
      const int row_ = k_ * 64 + trow0;                                        \
      const unsigned dst_ = (unsigned)(k_ * 4096) + udstw;                     \
      const size_t soff_ = (size_t)row_ * 128 + ((tci0 ^ (row_ & 3)) << 3);    \
      gl16(asrc + soff_, (char*)&As[BUF][0] + dst_);                           \
      gl16(bsrc + soff_, (char*)&Bs[BUF][0] + dst_);                           \
    }                                                                          \
  }

  f32x4 acc[4][4];
#pragma unroll
  for (int mt = 0; mt < 4; ++mt)
#pragma unroll
    for (int nt = 0; nt < 4; ++nt) acc[mt][nt] = (f32x4)0.f;

  STAGE(0, 0);
  __syncthreads();   // drains vmcnt -> buf0 ready

  int cur = 0;
#pragma unroll 1
  for (int s = 0; s < 36; ++s) {
    if (s + 1 < 36) STAGE(cur ^ 1, s + 1);   // async prefetch under MFMAs

    const char* Ab = (const char*)&As[cur][0];
    const char* Bb = (const char*)&Bs[cur][0];
    short8 af[4], bfr[4];
#pragma unroll
    for (int mt = 0; mt < 4; ++mt) {
      const int oc = oc0w + mt * 16 + lm;
      af[mt] = *(const short8*)(Ab + oc * 64 + ((lh ^ (oc & 3)) << 4));
    }
#pragma unroll
    for (int nt = 0; nt < 4; ++nt) {
      const int px = px0w + nt * 16 + lm;
      bfr[nt] = *(const short8*)(Bb + px * 64 + ((lh ^ (px & 3)) << 4));
    }
#pragma unroll
    for (int mt = 0; mt < 4; ++mt) {
      acc[mt][0] = mfma16(af[mt], bfr[0], acc[mt][0]);
      acc[mt][1] = mfma16(af[mt], bfr[1], acc[mt][1]);
      acc[mt][2] = mfma16(af[mt], bfr[2], acc[mt][2]);
      acc[mt][3] = mfma16(af[mt], bfr[3], acc[mt][3]);
    }
    __syncthreads();   // waits prefetch (vmcnt) + protects buf overwrite
    cur ^= 1;
  }
#undef STAGE

  // epilogue: per-oc constant terms (reuse As as f32 scratch)
  float* sm = (float*)&As[0][0];   // [3][128]: add, left, right
  if (tid < 128) {
    const float* Tk = ws + OFF_T + (size_t)(b * 128 + tid) * 9;
    float s = Tk[3] + Tk[4] + Tk[5], sl = Tk[3], sr = Tk[5];
    if (y >= 1)   { s += Tk[0] + Tk[1] + Tk[2]; sl += Tk[0]; sr += Tk[2]; }
    if (y <= 126) { s += Tk[6] + Tk[7] + Tk[8]; sl += Tk[6]; sr += Tk[8]; }
    sm[tid] = s + b_f[tid]; sm[128 + tid] = sl; sm[256 + tid] = sr;
  }
  __syncthreads();

#pragma unroll
  for (int mt = 0; mt < 4; ++mt)
#pragma unroll
    for (int nt = 0; nt < 4; ++nt) {
      const int px = px0w + nt * 16 + lm;
#pragma unroll
      for (int r = 0; r < 4; ++r) {
        const int oc = oc0w + mt * 16 + lh * 4 + r;
        float add = sm[oc];
        if (px == 0)   add -= sm[128 + oc];
        if (px == 127) add -= sm[256 + oc];
        const float z = acc[mt][nt][r] + add;
        const size_t base = ((size_t)(b * C_ + oc)) * HW_ + (size_t)y * W_ + px;
        const float rx = xin[base];
        out[base] = rx + (z >= 0.f ? z : 0.2f * z);
      }
    }
}

// K4 fallback (R2 version): used when ws_size can't hold T2.
__global__ __launch_bounds__(512, 4) void k_conv_fb(const float* __restrict__ xin,
                                                    const float* __restrict__ to,
                                                    const float* __restrict__ b_f,
                                                    const float* __restrict__ ws,
                                                    float* __restrict__ out) {
  const int bid = blockIdx.x;
  const int nb  = (bid & 7) * 128 + (bid >> 3);
  const int b   = nb >> 7;
  const int y   = nb & 127;
  const int tid = threadIdx.x;

  __shared__ f32x4 ldsbuf[3120];
  char* lp = (char*)ldsbuf;

  f32x4 acc[4][2];
#pragma unroll
  for (int mt = 0; mt < 4; ++mt)
#pragma unroll
    for (int nt = 0; nt < 2; ++nt) acc[mt][nt] = (f32x4)0.f;

  const float* tob = to + (size_t)b * C_ * HW_;
  const unsigned short* wb16 =
      (const unsigned short*)(ws + OFF_WEFF) + (size_t)b * 9 * 128 * 128;

  const int l = tid & 63, wv = tid >> 6;
  const int ocb0 = (wv & 1) * 64, pxb0 = (wv >> 1) * 32;
  const int lm = l & 15, lh = l >> 4;

  for (int cb = 0; cb < 128; cb += 64) {
    __syncthreads();
    {
      const int xg = tid & 31, cq = (tid >> 5) & 15;
      const int cbase = cb + cq * 4;
#pragma unroll
      for (int row = 0; row < 3; ++row) {
        const int y_in = y + row - 1;
        const bool yok = ((unsigned)y_in < 128u);
        const float* src = tob + (size_t)cbase * HW_ + (size_t)y_in * W_;
#pragma unroll
        for (int xb = 0; xb < 5; ++xb) {
          const int xi = xb * 32 + xg;
          if (xi < 130) {
            const int x_in = xi - 1;
            const bool ok = yok && ((unsigned)x_in < 128u);
            float f0 = 0.f, f1 = 0.f, f2 = 0.f, f3 = 0.f;
            if (ok) {
              f0 = src[x_in];
              f1 = src[HW_ + x_in];
              f2 = src[2 * HW_ + x_in];
              f3 = src[3 * HW_ + x_in];
            }
            ushort4 pk;
            pk.x = f2bf(f0); pk.y = f2bf(f1); pk.z = f2bf(f2); pk.w = f2bf(f3);
            const int boff = (row * 130 + xi) * 128 + ((cq * 8) ^ ((xi & 7) << 4));
            *(ushort4*)(lp + boff) = pk;
          }
        }
      }
    }
    __syncthreads();

    for (int tap = 0; tap < 9; ++tap) {
      const int dy = tap / 3, dx = tap - dy * 3;
#pragma unroll
      for (int ks = 0; ks < 2; ++ks) {
        short8 bfr[2];
#pragma unroll
        for (int nt = 0; nt < 2; ++nt) {
          const int xi = pxb0 + nt * 16 + lm + dx;
          const int boff = (dy * 130 + xi) * 128 + ((ks * 64 + lh * 16) ^ ((xi & 7) << 4));
          bfr[nt] = *(const short8*)(lp + boff);
        }
        const int cin = cb + ks * 32 + lh * 8;
#pragma unroll
        for (int mt = 0; mt < 4; ++mt) {
          const int oc = ocb0 + mt * 16 + lm;
          const short8 af = *(const short8*)(wb16 + ((size_t)tap * 128 + oc) * 128 + cin);
          acc[mt][0] = mfma16(af, bfr[0], acc[mt][0]);
          acc[mt][1] = mfma16(af, bfr[1], acc[mt][1]);
        }
      }
    }
  }

  __syncthreads();
  float* sAdd = (float*)ldsbuf;
  float* sLft = sAdd + 128;
  float* sRgt = sAdd + 256;
  if (tid < 128) {
    const float* Tk = ws + OFF_T + (size_t)(b * 128 + tid) * 9;
    float s = Tk[3] + Tk[4] + Tk[5], sl = Tk[3], sr = Tk[5];
    if (y >= 1)   { s += Tk[0] + Tk[1] + Tk[2]; sl += Tk[0]; sr += Tk[2]; }
    if (y <= 126) { s += Tk[6] + Tk[7] + Tk[8]; sl += Tk[6]; sr += Tk[8]; }
    sAdd[tid] = s + b_f[tid]; sLft[tid] = sl; sRgt[tid] = sr;
  }
  __syncthreads();

#pragma unroll
  for (int mt = 0; mt < 4; ++mt)
#pragma unroll
    for (int nt = 0; nt < 2; ++nt) {
      const int px = pxb0 + nt * 16 + lm;
#pragma unroll
      for (int r = 0; r < 4; ++r) {
        const int oc = ocb0 + mt * 16 + lh * 4 + r;
        float add = sAdd[oc];
        if (px == 0)   add -= sLft[oc];
        if (px == 127) add -= sRgt[oc];
        const float z = acc[mt][nt][r] + add;
        const size_t base = ((size_t)(b * C_ + oc)) * HW_ + (size_t)y * W_ + px;
        const float rx = xin[base];
        out[base] = rx + (z >= 0.f ? z : 0.2f * z);
      }
    }
}

extern "C" void kernel_launch(void* const* d_in, const int* in_sizes, int n_in,
                              void* d_out, int out_size, void* d_ws, size_t ws_size,
                              hipStream_t stream) {
  (void)in_sizes; (void)n_in; (void)out_size;
  const float* x    = (const float*)d_in[0];
  const float* to   = (const float*)d_in[1];
  const float* t    = (const float*)d_in[2];
  const float* w_r1 = (const float*)d_in[3];
  const float* b_r1 = (const float*)d_in[4];
  const float* w_r2 = (const float*)d_in[5];
  const float* b_r2 = (const float*)d_in[6];
  const float* w_r3 = (const float*)d_in[7];
  const float* b_r3 = (const float*)d_in[8];
  const float* w_t1 = (const float*)d_in[9];
  const float* b_t1 = (const float*)d_in[10];
  const float* w_t2 = (const float*)d_in[11];
  const float* b_t2 = (const float*)d_in[12];
  const float* w_t3 = (const float*)d_in[13];
  const float* b_t3 = (const float*)d_in[14];
  const float* w_f  = (const float*)d_in[15];
  const float* b_f  = (const float*)d_in[16];
  float* ws  = (float*)d_ws;
  float* out = (float*)d_out;
  unsigned short* t2 = (unsigned short*)(ws + OFF_T2F);
  const bool fast = (ws_size >= WS_NEED);

  k_gram<<<1024, 256, 0, stream>>>(x, to, ws);
  k_redB<<<80, 256, 0, stream>>>(ws);
  if (fast) {
    k_zero<<<16, 256, 0, stream>>>(t2);
    k_tr<<<2048, 256, 0, stream>>>(to, t2);
  }
  k_attn<<<8, 256, 0, stream>>>(t, w_r1, b_r1, w_r2, b_r2, w_r3, b_r3,
                                w_t1, b_t1, w_t2, b_t2, w_t3, b_t3, ws);
  k_weff<<<1024, 128, 0, stream>>>(w_f, ws);
  if (fast) k_conv<<<1024, 256, 0, stream>>>(x, b_f, ws, t2, out);
  else      k_conv_fb<<<1024, 512, 0, stream>>>(x, to, b_f, ws, out);
}

// Round 18
// 114.550 us; speedup vs baseline: 1.0516x; 1.0516x over previous
//
#include <hip/hip_runtime.h>
#include <math.h>

#define B_  8
#define C_  128
#define H_  128
#define W_  128
#define HW_ 16384

// ---- workspace layout (float offsets) ----
#define OFF_MPART 0          // [64 bblk][16 ps][256]     = 262144
#define OFF_SPART 262144     // [4 kind][1024 bc][16 ps]  = 65536
#define OFF_M     327680     // [64 bblk][256]            = 16384
#define OFF_S     344064     // [4 kind][1024 bc]         = 4096
#define OFF_WV    348160     // [8][16][16][16]           = 32768
#define OFF_CST   380928     // [8][256]                  = 2048
#define OFF_T     382976     // [8][128][9]               = 9216
#define OFF_WEFF  392192     // bf16 [8][9 tap][128 oc][128 cin] = 1179648 ushort = 589824 fl
#define OFF_T2F   982016     // bf16 T2 [8][130 y'][130 x'][128 c] = 17305600 ushort
#define T2_ROW    16640      // 130*128 shorts
#define T2_BATCH  2163200    // 130*16640 shorts
#define WS_NEED   (982016ull * 4ull + 34611200ull)

typedef __attribute__((ext_vector_type(8))) short short8;
typedef __attribute__((ext_vector_type(4))) float f32x4;

__device__ __forceinline__ unsigned short f2bf(float f) {
  unsigned u = __float_as_uint(f);
  u += 0x7fffu + ((u >> 16) & 1u);
  return (unsigned short)(u >> 16);
}

__device__ __forceinline__ f32x4 mfma16(short8 a, short8 b, f32x4 c) {
  return __builtin_amdgcn_mfma_f32_16x16x32_bf16(a, b, c, 0, 0, 0);
}

// async global->LDS 16B: HW dest = wave-uniform base + lane*16
__device__ __forceinline__ void gl16(const void* g, void* l) {
  const unsigned loff = (unsigned)(unsigned long long)l;
  __builtin_amdgcn_global_load_lds(
      (const __attribute__((address_space(1))) void*)g,
      (__attribute__((address_space(3))) void*)loff, 16, 0, 0);
}

// K1 (MFMA Gram): grid = b(8) x blk(8) x ps(16).
__global__ __launch_bounds__(256) void k_gram(const float* __restrict__ x,
                                              const float* __restrict__ to,
                                              float* __restrict__ ws) {
  const int bid = blockIdx.x;       // 0..1023
  const int ps  = bid & 15;
  const int blk = (bid >> 4) & 7;
  const int b   = bid >> 7;
  const int tid = threadIdx.x;
  const int w = tid >> 6, l = tid & 63;
  const int lm = l & 15, lh = l >> 4;
  const int c0 = blk * 16;

  const float* xc = x  + ((size_t)b * C_ + c0 + lm) * HW_;
  const float* tc = to + ((size_t)b * C_ + c0 + lm) * HW_;
  const int p0 = ps * 1024 + w * 256 + lh * 8;

  f32x4 acc = (f32x4)0.f;
  float sx = 0.f, sxx = 0.f, st = 0.f, stt = 0.f;
#pragma unroll
  for (int it = 0; it < 8; ++it) {
    const int p = p0 + it * 32;
    const f32x4 xa = *(const f32x4*)(xc + p);
    const f32x4 xb = *(const f32x4*)(xc + p + 4);
    const f32x4 ta = *(const f32x4*)(tc + p);
    const f32x4 tb = *(const f32x4*)(tc + p + 4);
    short8 xf, tf;
#pragma unroll
    for (int e = 0; e < 4; ++e) {
      xf[e]     = (short)f2bf(xa[e]);
      xf[4 + e] = (short)f2bf(xb[e]);
      tf[e]     = (short)f2bf(ta[e]);
      tf[4 + e] = (short)f2bf(tb[e]);
      sx += xa[e] + xb[e];
      sxx = fmaf(xa[e], xa[e], fmaf(xb[e], xb[e], sxx));
      st += ta[e] + tb[e];
      stt = fmaf(ta[e], ta[e], fmaf(tb[e], tb[e], stt));
    }
    acc = mfma16(xf, tf, acc);   // D[m=x-ch][n=to-ch]
  }

  sx  += __shfl_xor(sx, 16);  sx  += __shfl_xor(sx, 32);
  sxx += __shfl_xor(sxx, 16); sxx += __shfl_xor(sxx, 32);
  st  += __shfl_xor(st, 16);  st  += __shfl_xor(st, 32);
  stt += __shfl_xor(stt, 16); stt += __shfl_xor(stt, 32);

  __shared__ float smM[4][256];
  __shared__ float smS[4][4][16];
#pragma unroll
  for (int r = 0; r < 4; ++r)
    smM[w][(lh * 4 + r) * 16 + lm] = acc[r];   // row=(l>>4)*4+r, col=l&15 (m89)
  if (l < 16) {
    smS[w][0][lm] = sx;  smS[w][1][lm] = sxx;
    smS[w][2][lm] = st;  smS[w][3][lm] = stt;
  }
  __syncthreads();

  {
    const float s = smM[0][tid & 255] + smM[1][tid & 255]
                  + smM[2][tid & 255] + smM[3][tid & 255];
    ws[OFF_MPART + (size_t)((b * 8 + blk) * 16 + ps) * 256 + tid] = s;
  }
  if (tid < 64) {
    const int kind = tid >> 4, ch = tid & 15;
    const float s = smS[0][kind][ch] + smS[1][kind][ch]
                  + smS[2][kind][ch] + smS[3][kind][ch];
    ws[OFF_SPART + (size_t)kind * 16384 + (size_t)(b * C_ + c0 + ch) * 16 + ps] = s;
  }
}

// K1b: parallel reduction of partials (16 ps slices).
__global__ __launch_bounds__(256) void k_redB(float* __restrict__ ws) {
  const int gid = blockIdx.x * 256 + threadIdx.x;   // 80*256 = 20480
  if (gid < 16384) {
    const float* mp = ws + OFF_MPART + (size_t)(gid >> 8) * 4096 + (gid & 255);
    float s = 0.f;
#pragma unroll
    for (int kc = 0; kc < 16; ++kc) s += mp[kc * 256];
    ws[OFF_M + gid] = s;
  } else {
    const int sidx = gid - 16384;
    const float* sp = ws + OFF_SPART + (size_t)sidx * 16;
    float s = 0.f;
#pragma unroll
    for (int kc = 0; kc < 16; ++kc) s += sp[kc];
    ws[OFF_S + sidx] = s;
  }
}

// K_zero: zero T2 rows y'=0 and y'=129 for each batch.
__global__ __launch_bounds__(256) void k_zero(unsigned short* __restrict__ t2) {
  const int b = blockIdx.x >> 1, r = blockIdx.x & 1;
  unsigned short* row = t2 + (size_t)b * T2_BATCH + (size_t)(r ? 129 : 0) * T2_ROW;
  const short8 z = {0,0,0,0,0,0,0,0};
  for (int idx = threadIdx.x; idx < 2080; idx += 256)
    *(short8*)(row + (size_t)idx * 8) = z;
}

// K_tr: transpose to -> bf16 T2[b][y'][x'][c], y'=y+1, x'=x+1. float4 loads.
__global__ __launch_bounds__(256) void k_tr(const float* __restrict__ to,
                                            unsigned short* __restrict__ t2) {
  const int d  = blockIdx.x;          // 2048 = xh(2) * y(128) * b(8)
  const int xh = d & 1;
  const int y  = (d >> 1) & 127;
  const int b  = d >> 8;
  const int tid = threadIdx.x;
  __shared__ char lds[64 * 256];      // 16 KB

  const int x0 = xh * 64;
  const int xq = tid & 15;            // x-quad: x0 + xq*4 .. +3
  const int cg = tid >> 4;            // channel group: cg*8 .. +7
  const float* srcb = to + ((size_t)b * C_ + cg * 8) * HW_ + (size_t)y * W_ + x0 + xq * 4;
#pragma unroll
  for (int k = 0; k < 8; ++k) {
    const f32x4 v = *(const f32x4*)(srcb + (size_t)k * HW_);
    const int c = cg * 8 + k;
#pragma unroll
    for (int e = 0; e < 4; ++e) {
      const int xl = xq * 4 + e;
      const int boff = xl * 256 + ((2 * c) ^ ((xl & 7) << 4));
      *(unsigned short*)(lds + boff) = f2bf(v[e]);
    }
  }
  __syncthreads();

  unsigned short* rowbase = t2 + (size_t)b * T2_BATCH + (size_t)(y + 1) * T2_ROW;
#pragma unroll
  for (int i = 0; i < 4; ++i) {
    const int xx = tid >> 2;
    const int cs = (tid & 3) + i * 4;   // 0..15
    short8 val = *(short8*)(lds + xx * 256 + ((cs * 16) ^ ((xx & 7) << 4)));
    *(short8*)(rowbase + (size_t)(x0 + xx + 1) * 128 + cs * 8) = val;
  }
  if (tid < 16) {
    short8 z = {0,0,0,0,0,0,0,0};
    if (xh == 0) *(short8*)(rowbase + tid * 8) = z;
    else         *(short8*)(rowbase + (size_t)129 * 128 + tid * 8) = z;
  }
}

// K2 (parallel): one block per batch, thread = (h, i).
__global__ __launch_bounds__(256) void k_attn(const float* __restrict__ t,
    const float* __restrict__ w_r1, const float* __restrict__ b_r1,
    const float* __restrict__ w_r2, const float* __restrict__ b_r2,
    const float* __restrict__ w_r3, const float* __restrict__ b_r3,
    const float* __restrict__ w_t1, const float* __restrict__ b_t1,
    const float* __restrict__ w_t2, const float* __restrict__ b_t2,
    const float* __restrict__ w_t3, const float* __restrict__ b_t3,
    float* __restrict__ ws) {
  const int b = blockIdx.x;          // 0..7
  const int tid = threadIdx.x;       // h = tid>>4, i = tid&15
  __shared__ float aQ[256], bQ[256], aK[256], bK[256], aV[256], bV[256];
  __shared__ float rks[256], kAs[256], kBs[256], stos[256];

  if (tid < 128) {
    const int g = tid;
    float A1[4], B1[4], A2[2], B2[2];
#pragma unroll
    for (int j = 0; j < 4; ++j) { A1[j] = w_r1[g * 4 + j]; B1[j] = b_r1[g * 4 + j]; }
#pragma unroll
    for (int i = 0; i < 2; ++i) {
      A2[i] = 0.f; B2[i] = b_r2[g * 2 + i];
#pragma unroll
      for (int j = 0; j < 4; ++j) {
        const float w = w_r2[(g * 2 + i) * 4 + j];
        A2[i] = fmaf(w, A1[j], A2[i]); B2[i] = fmaf(w, B1[j], B2[i]);
      }
    }
#pragma unroll
    for (int o = 0; o < 2; ++o) {
      float a = 0.f, bb = b_r3[g * 2 + o];
#pragma unroll
      for (int i = 0; i < 2; ++i) {
        const float w = w_r3[(g * 2 + o) * 2 + i];
        a = fmaf(w, A2[i], a); bb = fmaf(w, B2[i], bb);
      }
      aQ[g * 2 + o] = a; bQ[g * 2 + o] = bb;
    }
#pragma unroll
    for (int j = 0; j < 4; ++j) { A1[j] = w_t1[g * 4 + j]; B1[j] = b_t1[g * 4 + j]; }
#pragma unroll
    for (int i = 0; i < 2; ++i) {
      A2[i] = 0.f; B2[i] = b_t2[g * 2 + i];
#pragma unroll
      for (int j = 0; j < 4; ++j) {
        const float w = w_t2[(g * 2 + i) * 4 + j];
        A2[i] = fmaf(w, A1[j], A2[i]); B2[i] = fmaf(w, B1[j], B2[i]);
      }
    }
#pragma unroll
    for (int o = 0; o < 4; ++o) {
      float a = 0.f, bb = b_t3[g * 4 + o];
#pragma unroll
      for (int i = 0; i < 2; ++i) {
        const float w = w_t3[(g * 4 + o) * 2 + i];
        a = fmaf(w, A2[i], a); bb = fmaf(w, B2[i], bb);
      }
      if (o < 2) { aK[g * 2 + o] = a; bK[g * 2 + o] = bb; }
      else       { aV[g * 2 + (o - 2)] = a; bV[g * 2 + (o - 2)] = bb; }
    }
  }
  __syncthreads();

  const float* S   = ws + OFF_S;
  const float* Sx  = S;
  const float* Sxx = S + 1024;
  const float* Sto = S + 2048;
  const float* Stt = S + 3072;

  {
    const int h = tid >> 4, e = h >> 3, blk = h & 7, c0 = blk * 16;
    const int g = c0 + (tid & 15);
    const float a = aK[g * 2 + e], bb = bK[g * 2 + e];
    const float s2 = a * a * Stt[b * C_ + g] + 2.f * a * bb * Sto[b * C_ + g]
                   + bb * bb * 16384.f;
    rks[tid] = 1.f / fmaxf(sqrtf(fmaxf(s2, 0.f)), 1e-12f);
    kAs[tid] = a; kBs[tid] = bb;
    stos[tid] = Sto[b * C_ + g];
  }
  __syncthreads();

  {
    const int h = tid >> 4, i = tid & 15, e = h >> 3, blk = h & 7, c0 = blk * 16;
    const int gi = c0 + i;
    const float gA = aQ[gi * 2 + e], gB = bQ[gi * 2 + e];
    const float sxi = Sx[b * C_ + gi];
    const float q2 = gA * gA * Sxx[b * C_ + gi] + 2.f * gA * gB * sxi
                   + gB * gB * 16384.f;
    const float rnq = 1.f / fmaxf(sqrtf(fmaxf(q2, 0.f)), 1e-12f);
    const float tt = t[h];
    const float* Mrow = ws + OFF_M + (size_t)(b * 8 + blk) * 256 + i * 16;

    float lg[16];
    float mx = -1e30f;
#pragma unroll
    for (int j = 0; j < 16; ++j) {
      const float s = gA * kAs[h * 16 + j] * Mrow[j]
                    + gA * kBs[h * 16 + j] * sxi
                    + gB * kAs[h * 16 + j] * stos[h * 16 + j]
                    + gB * kBs[h * 16 + j] * 16384.f;
      const float l = tt * s * rnq * rks[h * 16 + j];
      lg[j] = l;
      mx = fmaxf(mx, l);
    }
    float den = 0.f;
#pragma unroll
    for (int j = 0; j < 16; ++j) { const float ev = expf(lg[j] - mx); lg[j] = ev; den += ev; }
    const float inv = 1.f / den;
    float cs = 0.f;
    float* WVp = ws + OFF_WV + (size_t)(b * 16 + h) * 256 + i * 16;
#pragma unroll
    for (int j = 0; j < 16; ++j) {
      const float aa = lg[j] * inv;
      const int gj = c0 + j;
      WVp[j] = aa * aV[gj * 2 + e];
      cs = fmaf(aa, bV[gj * 2 + e], cs);
    }
    ws[OFF_CST + b * 256 + i * 16 + h] = cs;
  }
}

// K3: fold attention into per-batch bf16 conv weights + constant taps.
__global__ __launch_bounds__(128) void k_weff(const float* __restrict__ w_f,
                                              float* __restrict__ ws) {
  const int b = blockIdx.x >> 7, oc = blockIdx.x & 127;
  const int c = threadIdx.x, blk = c >> 4, j = c & 15;
  const float* WVb = ws + OFF_WV;
  float acc[9];
#pragma unroll
  for (int k = 0; k < 9; ++k) acc[k] = 0.f;
#pragma unroll
  for (int e = 0; e < 2; ++e) {
    const int h = e * 8 + blk;
#pragma unroll
    for (int i = 0; i < 16; ++i) {
      const float coef = WVb[((size_t)(b * 16 + h) * 16 + i) * 16 + j];
      const float* wf = w_f + (size_t)(oc * 256 + i * 16 + h) * 9;
#pragma unroll
      for (int k = 0; k < 9; ++k) acc[k] = fmaf(wf[k], coef, acc[k]);
    }
  }
  unsigned short* wb16 = (unsigned short*)(ws + OFF_WEFF);
#pragma unroll
  for (int k = 0; k < 9; ++k)
    wb16[(((size_t)(b * 9 + k)) * 128 + oc) * 128 + c] = f2bf(acc[k]);

  __shared__ float tp[9][128];
  float tl[9];
#pragma unroll
  for (int k = 0; k < 9; ++k) tl[k] = 0.f;
  const float* cst = ws + OFF_CST + b * 256;
  for (int cc = c; cc < 256; cc += 128) {
    const float cv = cst[cc];
    const float* wf = w_f + (size_t)(oc * 256 + cc) * 9;
#pragma unroll
    for (int k = 0; k < 9; ++k) tl[k] = fmaf(wf[k], cv, tl[k]);
  }
#pragma unroll
  for (int k = 0; k < 9; ++k) tp[k][c] = tl[k];
  __syncthreads();
  for (int s = 64; s > 0; s >>= 1) {
    if (c < s) {
#pragma unroll
      for (int k = 0; k < 9; ++k) tp[k][c] += tp[k][c + s];
    }
    __syncthreads();
  }
  if (c < 9) ws[OFF_T + ((size_t)b * 128 + oc) * 9 + c] = tp[c][0];
}

// K4: 2-row block (traffic-minimized). Block = (b, y-pair). 512 thr, 8 waves:
// wave = (row = wv>>2, px-half = (wv>>1)&1, oc-half = wv&1), tile 64oc x 64px.
// Per ks-half (64 cin): B4[4 T2 rows][130 x'][64 cin] staged ONCE (66.5 KB),
// A[2][128][64] double-buffered per tap. Staging: 421 KB/block vs 1152 before.
__global__ __launch_bounds__(512, 2) void k_conv(const float* __restrict__ xin,
                                                 const float* __restrict__ b_f,
                                                 const float* __restrict__ ws,
                                                 const unsigned short* __restrict__ t2,
                                                 float* __restrict__ out) {
  const int d  = blockIdx.x;          // 512 = b(8, fast -> XCD) * y2(64)
  const int b  = d & 7;
  const int y2 = d >> 3;
  const int tid = threadIdx.x;

  __shared__ unsigned short B4s[33280];     // 66,560 B: [4][130][64] swizzled
  __shared__ unsigned short As[2][8192];    // 32,768 B: [2][128 oc][64 cin]

  const unsigned short* wb = (const unsigned short*)(ws + OFF_WEFF)
      + (size_t)b * 9 * 16384;
  const unsigned short* t2b4 = t2 + (size_t)b * T2_BATCH
      + (size_t)(y2 * 2) * T2_ROW;

  const int l = tid & 63;
  const int lm = l & 15, lh = l >> 4;
  const int wv = tid >> 6;            // 0..7
  const int oc0w = (wv & 1) * 64;
  const int px0w = ((wv >> 1) & 1) * 64;
  const int rw   = wv >> 2;           // output row within pair

  const unsigned udstw = (unsigned)((tid & ~63) * 16);

  // B4 stage: 4160 16B tasks; q -> rr = q/1040, xi = (q%1040)>>3, c8 = q&7
#define STAGE_B4(KS)                                                           \
  {                                                                            \
    _Pragma("unroll")                                                          \
    for (int i_ = 0; i_ < 8; ++i_) {                                           \
      const int q_ = i_ * 512 + tid;                                           \
      const int rr_ = q_ / 1040;                                               \
      const int rem_ = q_ - rr_ * 1040;                                        \
      const int xi_ = rem_ >> 3, c8_ = rem_ & 7;                               \
      gl16(t2b4 + (size_t)rr_ * T2_ROW + xi_ * 128 + (KS) * 64                 \
               + ((c8_ ^ (xi_ & 7)) << 3),                                     \
           (char*)B4s + (unsigned)(i_ * 8192) + udstw);                        \
    }                                                                          \
    if (tid < 64) {                                                            \
      const int q_ = 4096 + tid;                                               \
      const int rr_ = q_ / 1040;                                               \
      const int rem_ = q_ - rr_ * 1040;                                        \
      const int xi_ = rem_ >> 3, c8_ = rem_ & 7;                               \
      gl16(t2b4 + (size_t)rr_ * T2_ROW + xi_ * 128 + (KS) * 64                 \
               + ((c8_ ^ (xi_ & 7)) << 3),                                     \
           (char*)B4s + 65536u);                                               \
    }                                                                          \
  }

#define STAGE_A(BUF, TAP, KS)                                                  \
  {                                                                            \
    const unsigned short* asrc = wb + (size_t)(TAP) * 16384 + (KS) * 64;       \
    _Pragma("unroll")                                                          \
    for (int k_ = 0; k_ < 2; ++k_) {                                           \
      const int task_ = k_ * 512 + tid;                                        \
      const int trow_ = task_ >> 3, c8_ = task_ & 7;                           \
      gl16(asrc + (size_t)trow_ * 128 + ((c8_ ^ (trow_ & 7)) << 3),            \
           (char*)&As[BUF][0] + (unsigned)(k_ * 8192) + udstw);                \
    }                                                                          \
  }

  f32x4 acc[4][4];
#pragma unroll
  for (int mt = 0; mt < 4; ++mt)
#pragma unroll
    for (int nt = 0; nt < 4; ++nt) acc[mt][nt] = (f32x4)0.f;

#pragma unroll 1
  for (int ks = 0; ks < 2; ++ks) {
    STAGE_B4(ks);
    STAGE_A(0, 0, ks);
    __syncthreads();   // drains all staging (vmcnt 0 at barrier)

    int cur = 0;
#pragma unroll 1
    for (int tap = 0; tap < 9; ++tap) {
      if (tap + 1 < 9) STAGE_A(cur ^ 1, tap + 1, ks);   // prefetch under MFMAs

      const int dy = tap / 3, dx = tap - dy * 3;
      const int rdy = rw + dy;                    // B4 row 0..3
      const char* Ab = (const char*)&As[cur][0];
      const char* Bb = (const char*)B4s;
#pragma unroll
      for (int ki = 0; ki < 2; ++ki) {
        short8 af[4], bfr[4];
#pragma unroll
        for (int mt = 0; mt < 4; ++mt) {
          const int oc = oc0w + mt * 16 + lm;
          af[mt] = *(const short8*)(Ab + oc * 128 + (((ki * 4 + lh) ^ (oc & 7)) << 4));
        }
#pragma unroll
        for (int nt = 0; nt < 4; ++nt) {
          const int xi = px0w + nt * 16 + lm + dx;
          bfr[nt] = *(const short8*)(Bb + (rdy * 130 + xi) * 128
                                        + (((ki * 4 + lh) ^ (xi & 7)) << 4));
        }
#pragma unroll
        for (int mt = 0; mt < 4; ++mt) {
          acc[mt][0] = mfma16(af[mt], bfr[0], acc[mt][0]);
          acc[mt][1] = mfma16(af[mt], bfr[1], acc[mt][1]);
          acc[mt][2] = mfma16(af[mt], bfr[2], acc[mt][2]);
          acc[mt][3] = mfma16(af[mt], bfr[3], acc[mt][3]);
        }
      }
      __syncthreads();   // waits A prefetch + protects buf/B4 overwrite
      cur ^= 1;
    }
  }
#undef STAGE_A
#undef STAGE_B4

  // epilogue: per (row, oc) constant terms (reuse B4s as f32 scratch)
  float* sm = (float*)B4s;   // [2][384]: add, left, right per row
  if (tid < 256) {
    const int rr = tid >> 7, oc = tid & 127;
    const int y = y2 * 2 + rr;
    const float* Tk = ws + OFF_T + (size_t)(b * 128 + oc) * 9;
    float s = Tk[3] + Tk[4] + Tk[5], sl = Tk[3], sr = Tk[5];
    if (y >= 1)   { s += Tk[0] + Tk[1] + Tk[2]; sl += Tk[0]; sr += Tk[2]; }
    if (y <= 126) { s += Tk[6] + Tk[7] + Tk[8]; sl += Tk[6]; sr += Tk[8]; }
    sm[rr * 384 + oc] = s + b_f[oc];
    sm[rr * 384 + 128 + oc] = sl;
    sm[rr * 384 + 256 + oc] = sr;
  }
  __syncthreads();

  const int y = y2 * 2 + rw;
#pragma unroll
  for (int mt = 0; mt < 4; ++mt)
#pragma unroll
    for (int nt = 0; nt < 4; ++nt) {
      const int px = px0w + nt * 16 + lm;
#pragma unroll
      for (int r = 0; r < 4; ++r) {
        const int oc = oc0w + mt * 16 + lh * 4 + r;
        float add = sm[rw * 384 + oc];
        if (px == 0)   add -= sm[rw * 384 + 128 + oc];
        if (px == 127) add -= sm[rw * 384 + 256 + oc];
        const float z = acc[mt][nt][r] + add;
        const size_t base = ((size_t)(b * C_ + oc)) * HW_ + (size_t)y * W_ + px;
        const float rx = xin[base];
        out[base] = rx + (z >= 0.f ? z : 0.2f * z);
      }
    }
}

// K4 fallback (R2 version): used when ws_size can't hold T2.
__global__ __launch_bounds__(512, 4) void k_conv_fb(const float* __restrict__ xin,
                                                    const float* __restrict__ to,
                                                    const float* __restrict__ b_f,
                                                    const float* __restrict__ ws,
                                                    float* __restrict__ out) {
  const int bid = blockIdx.x;
  const int nb  = (bid & 7) * 128 + (bid >> 3);
  const int b   = nb >> 7;
  const int y   = nb & 127;
  const int tid = threadIdx.x;

  __shared__ f32x4 ldsbuf[3120];
  char* lp = (char*)ldsbuf;

  f32x4 acc[4][2];
#pragma unroll
  for (int mt = 0; mt < 4; ++mt)
#pragma unroll
    for (int nt = 0; nt < 2; ++nt) acc[mt][nt] = (f32x4)0.f;

  const float* tob = to + (size_t)b * C_ * HW_;
  const unsigned short* wb16 =
      (const unsigned short*)(ws + OFF_WEFF) + (size_t)b * 9 * 128 * 128;

  const int l = tid & 63, wv = tid >> 6;
  const int ocb0 = (wv & 1) * 64, pxb0 = (wv >> 1) * 32;
  const int lm = l & 15, lh = l >> 4;

  for (int cb = 0; cb < 128; cb += 64) {
    __syncthreads();
    {
      const int xg = tid & 31, cq = (tid >> 5) & 15;
      const int cbase = cb + cq * 4;
#pragma unroll
      for (int row = 0; row < 3; ++row) {
        const int y_in = y + row - 1;
        const bool yok = ((unsigned)y_in < 128u);
        const float* src = tob + (size_t)cbase * HW_ + (size_t)y_in * W_;
#pragma unroll
        for (int xb = 0; xb < 5; ++xb) {
          const int xi = xb * 32 + xg;
          if (xi < 130) {
            const int x_in = xi - 1;
            const bool ok = yok && ((unsigned)x_in < 128u);
            float f0 = 0.f, f1 = 0.f, f2 = 0.f, f3 = 0.f;
            if (ok) {
              f0 = src[x_in];
              f1 = src[HW_ + x_in];
              f2 = src[2 * HW_ + x_in];
              f3 = src[3 * HW_ + x_in];
            }
            ushort4 pk;
            pk.x = f2bf(f0); pk.y = f2bf(f1); pk.z = f2bf(f2); pk.w = f2bf(f3);
            const int boff = (row * 130 + xi) * 128 + ((cq * 8) ^ ((xi & 7) << 4));
            *(ushort4*)(lp + boff) = pk;
          }
        }
      }
    }
    __syncthreads();

    for (int tap = 0; tap < 9; ++tap) {
      const int dy = tap / 3, dx = tap - dy * 3;
#pragma unroll
      for (int ks = 0; ks < 2; ++ks) {
        short8 bfr[2];
#pragma unroll
        for (int nt = 0; nt < 2; ++nt) {
          const int xi = pxb0 + nt * 16 + lm + dx;
          const int boff = (dy * 130 + xi) * 128 + ((ks * 64 + lh * 16) ^ ((xi & 7) << 4));
          bfr[nt] = *(const short8*)(lp + boff);
        }
        const int cin = cb + ks * 32 + lh * 8;
#pragma unroll
        for (int mt = 0; mt < 4; ++mt) {
          const int oc = ocb0 + mt * 16 + lm;
          const short8 af = *(const short8*)(wb16 + ((size_t)tap * 128 + oc) * 128 + cin);
          acc[mt][0] = mfma16(af, bfr[0], acc[mt][0]);
          acc[mt][1] = mfma16(af, bfr[1], acc[mt][1]);
        }
      }
    }
  }

  __syncthreads();
  float* sAdd = (float*)ldsbuf;
  float* sLft = sAdd + 128;
  float* sRgt = sAdd + 256;
  if (tid < 128) {
    const float* Tk = ws + OFF_T + (size_t)(b * 128 + tid) * 9;
    float s = Tk[3] + Tk[4] + Tk[5], sl = Tk[3], sr = Tk[5];
    if (y >= 1)   { s += Tk[0] + Tk[1] + Tk[2]; sl += Tk[0]; sr += Tk[2]; }
    if (y <= 126) { s += Tk[6] + Tk[7] + Tk[8]; sl += Tk[6]; sr += Tk[8]; }
    sAdd[tid] = s + b_f[tid]; sLft[tid] = sl; sRgt[tid] = sr;
  }
  __syncthreads();

#pragma unroll
  for (int mt = 0; mt < 4; ++mt)
#pragma unroll
    for (int nt = 0; nt < 2; ++nt) {
      const int px = pxb0 + nt * 16 + lm;
#pragma unroll
      for (int r = 0; r < 4; ++r) {
        const int oc = ocb0 + mt * 16 + lh * 4 + r;
        float add = sAdd[oc];
        if (px == 0)   add -= sLft[oc];
        if (px == 127) add -= sRgt[oc];
        const float z = acc[mt][nt][r] + add;
        const size_t base = ((size_t)(b * C_ + oc)) * HW_ + (size_t)y * W_ + px;
        const float rx = xin[base];
        out[base] = rx + (z >= 0.f ? z : 0.2f * z);
      }
    }
}

extern "C" void kernel_launch(void* const* d_in, const int* in_sizes, int n_in,
                              void* d_out, int out_size, void* d_ws, size_t ws_size,
                              hipStream_t stream) {
  (void)in_sizes; (void)n_in; (void)out_size;
  const float* x    = (const float*)d_in[0];
  const float* to   = (const float*)d_in[1];
  const float* t    = (const float*)d_in[2];
  const float* w_r1 = (const float*)d_in[3];
  const float* b_r1 = (const float*)d_in[4];
  const float* w_r2 = (const float*)d_in[5];
  const float* b_r2 = (const float*)d_in[6];
  const float* w_r3 = (const float*)d_in[7];
  const float* b_r3 = (const float*)d_in[8];
  const float* w_t1 = (const float*)d_in[9];
  const float* b_t1 = (const float*)d_in[10];
  const float* w_t2 = (const float*)d_in[11];
  const float* b_t2 = (const float*)d_in[12];
  const float* w_t3 = (const float*)d_in[13];
  const float* b_t3 = (const float*)d_in[14];
  const float* w_f  = (const float*)d_in[15];
  const float* b_f  = (const float*)d_in[16];
  float* ws  = (float*)d_ws;
  float* out = (float*)d_out;
  unsigned short* t2 = (unsigned short*)(ws + OFF_T2F);
  const bool fast = (ws_size >= WS_NEED);

  k_gram<<<1024, 256, 0, stream>>>(x, to, ws);
  k_redB<<<80, 256, 0, stream>>>(ws);
  if (fast) {
    k_zero<<<16, 256, 0, stream>>>(t2);
    k_tr<<<2048, 256, 0, stream>>>(to, t2);
  }
  k_attn<<<8, 256, 0, stream>>>(t, w_r1, b_r1, w_r2, b_r2, w_r3, b_r3,
                                w_t1, b_t1, w_t2, b_t2, w_t3, b_t3, ws);
  k_weff<<<1024, 128, 0, stream>>>(w_f, ws);
  if (fast) k_conv<<<512, 512, 0, stream>>>(x, b_f, ws, t2, out);
  else      k_conv_fb<<<1024, 512, 0, stream>>>(x, to, b_f, ws, out);
}

// Round 19
// 111.823 us; speedup vs baseline: 1.0773x; 1.0244x over previous
//
#include <hip/hip_runtime.h>
#include <math.h>

#define B_  8
#define C_  128
#define H_  128
#define W_  128
#define HW_ 16384

// ---- workspace layout (float offsets) ----
#define OFF_MPART 0          // [64 bblk][16 ps][256]     = 262144
#define OFF_SPART 262144     // [4 kind][1024 bc][16 ps]  = 65536
#define OFF_WV    348160     // [8][16][16][16]           = 32768
#define OFF_CST   380928     // [8][256]                  = 2048
#define OFF_T     382976     // [8][128][9]               = 9216
#define OFF_WEFF  392192     // bf16 [8][9 tap][128 oc][128 cin] = 1179648 ushort = 589824 fl
#define OFF_T2F   982016     // bf16 T2 [8][130 y'][130 x'][128 c] = 17305600 ushort
#define T2_ROW    16640      // 130*128 shorts
#define T2_BATCH  2163200    // 130*16640 shorts
#define WS_NEED   (982016ull * 4ull + 34611200ull)

typedef __attribute__((ext_vector_type(8))) short short8;
typedef __attribute__((ext_vector_type(4))) float f32x4;

__device__ __forceinline__ unsigned short f2bf(float f) {
  unsigned u = __float_as_uint(f);
  u += 0x7fffu + ((u >> 16) & 1u);
  return (unsigned short)(u >> 16);
}

__device__ __forceinline__ f32x4 mfma16(short8 a, short8 b, f32x4 c) {
  return __builtin_amdgcn_mfma_f32_16x16x32_bf16(a, b, c, 0, 0, 0);
}

// async global->LDS 16B: HW dest = wave-uniform base + lane*16
__device__ __forceinline__ void gl16(const void* g, void* l) {
  const unsigned loff = (unsigned)(unsigned long long)l;
  __builtin_amdgcn_global_load_lds(
      (const __attribute__((address_space(1))) void*)g,
      (__attribute__((address_space(3))) void*)loff, 16, 0, 0);
}

// K1 (MFMA Gram): grid = b(8) x blk(8) x ps(16).
__global__ __launch_bounds__(256) void k_gram(const float* __restrict__ x,
                                              const float* __restrict__ to,
                                              float* __restrict__ ws) {
  const int bid = blockIdx.x;       // 0..1023
  const int ps  = bid & 15;
  const int blk = (bid >> 4) & 7;
  const int b   = bid >> 7;
  const int tid = threadIdx.x;
  const int w = tid >> 6, l = tid & 63;
  const int lm = l & 15, lh = l >> 4;
  const int c0 = blk * 16;

  const float* xc = x  + ((size_t)b * C_ + c0 + lm) * HW_;
  const float* tc = to + ((size_t)b * C_ + c0 + lm) * HW_;
  const int p0 = ps * 1024 + w * 256 + lh * 8;

  f32x4 acc = (f32x4)0.f;
  float sx = 0.f, sxx = 0.f, st = 0.f, stt = 0.f;
#pragma unroll
  for (int it = 0; it < 8; ++it) {
    const int p = p0 + it * 32;
    const f32x4 xa = *(const f32x4*)(xc + p);
    const f32x4 xb = *(const f32x4*)(xc + p + 4);
    const f32x4 ta = *(const f32x4*)(tc + p);
    const f32x4 tb = *(const f32x4*)(tc + p + 4);
    short8 xf, tf;
#pragma unroll
    for (int e = 0; e < 4; ++e) {
      xf[e]     = (short)f2bf(xa[e]);
      xf[4 + e] = (short)f2bf(xb[e]);
      tf[e]     = (short)f2bf(ta[e]);
      tf[4 + e] = (short)f2bf(tb[e]);
      sx += xa[e] + xb[e];
      sxx = fmaf(xa[e], xa[e], fmaf(xb[e], xb[e], sxx));
      st += ta[e] + tb[e];
      stt = fmaf(ta[e], ta[e], fmaf(tb[e], tb[e], stt));
    }
    acc = mfma16(xf, tf, acc);   // D[m=x-ch][n=to-ch]
  }

  sx  += __shfl_xor(sx, 16);  sx  += __shfl_xor(sx, 32);
  sxx += __shfl_xor(sxx, 16); sxx += __shfl_xor(sxx, 32);
  st  += __shfl_xor(st, 16);  st  += __shfl_xor(st, 32);
  stt += __shfl_xor(stt, 16); stt += __shfl_xor(stt, 32);

  __shared__ float smM[4][256];
  __shared__ float smS[4][4][16];
#pragma unroll
  for (int r = 0; r < 4; ++r)
    smM[w][(lh * 4 + r) * 16 + lm] = acc[r];   // row=(l>>4)*4+r, col=l&15 (m89)
  if (l < 16) {
    smS[w][0][lm] = sx;  smS[w][1][lm] = sxx;
    smS[w][2][lm] = st;  smS[w][3][lm] = stt;
  }
  __syncthreads();

  {
    const float s = smM[0][tid & 255] + smM[1][tid & 255]
                  + smM[2][tid & 255] + smM[3][tid & 255];
    ws[OFF_MPART + (size_t)((b * 8 + blk) * 16 + ps) * 256 + tid] = s;
  }
  if (tid < 64) {
    const int kind = tid >> 4, ch = tid & 15;
    const float s = smS[0][kind][ch] + smS[1][kind][ch]
                  + smS[2][kind][ch] + smS[3][kind][ch];
    ws[OFF_SPART + (size_t)kind * 16384 + (size_t)(b * C_ + c0 + ch) * 16 + ps] = s;
  }
}

// K_trz: transpose to -> bf16 T2[b][y'][x'][c] (blocks 0..2047), plus border
// zero rows y'=0/129 (blocks 2048..2063). Fused k_tr + k_zero.
__global__ __launch_bounds__(256) void k_trz(const float* __restrict__ to,
                                             unsigned short* __restrict__ t2) {
  const int d  = blockIdx.x;
  const int tid = threadIdx.x;
  if (d >= 2048) {
    const int e = d - 2048;          // 0..15: b(8) x r(2)
    const int b = e >> 1, r = e & 1;
    unsigned short* row = t2 + (size_t)b * T2_BATCH + (size_t)(r ? 129 : 0) * T2_ROW;
    const short8 z = {0,0,0,0,0,0,0,0};
    for (int idx = tid; idx < 2080; idx += 256)
      *(short8*)(row + (size_t)idx * 8) = z;
    return;
  }
  const int xh = d & 1;
  const int y  = (d >> 1) & 127;
  const int b  = d >> 8;
  __shared__ char lds[64 * 256];      // 16 KB

  const int x0 = xh * 64;
  const int xq = tid & 15;            // x-quad
  const int cg = tid >> 4;            // channel group
  const float* srcb = to + ((size_t)b * C_ + cg * 8) * HW_ + (size_t)y * W_ + x0 + xq * 4;
#pragma unroll
  for (int k = 0; k < 8; ++k) {
    const f32x4 v = *(const f32x4*)(srcb + (size_t)k * HW_);
    const int c = cg * 8 + k;
#pragma unroll
    for (int e = 0; e < 4; ++e) {
      const int xl = xq * 4 + e;
      const int boff = xl * 256 + ((2 * c) ^ ((xl & 7) << 4));
      *(unsigned short*)(lds + boff) = f2bf(v[e]);
    }
  }
  __syncthreads();

  unsigned short* rowbase = t2 + (size_t)b * T2_BATCH + (size_t)(y + 1) * T2_ROW;
#pragma unroll
  for (int i = 0; i < 4; ++i) {
    const int xx = tid >> 2;
    const int cs = (tid & 3) + i * 4;   // 0..15
    short8 val = *(short8*)(lds + xx * 256 + ((cs * 16) ^ ((xx & 7) << 4)));
    *(short8*)(rowbase + (size_t)(x0 + xx + 1) * 128 + cs * 8) = val;
  }
  if (tid < 16) {
    short8 z = {0,0,0,0,0,0,0,0};
    if (xh == 0) *(short8*)(rowbase + tid * 8) = z;
    else         *(short8*)(rowbase + (size_t)129 * 128 + tid * 8) = z;
  }
}

// K2 (fused redB+attn): one block per batch. Phase B0: reduce this batch's
// partials into LDS. Phase A: coefficient folding. Phase C: logits/softmax.
__global__ __launch_bounds__(256) void k_attn(const float* __restrict__ t,
    const float* __restrict__ w_r1, const float* __restrict__ b_r1,
    const float* __restrict__ w_r2, const float* __restrict__ b_r2,
    const float* __restrict__ w_r3, const float* __restrict__ b_r3,
    const float* __restrict__ w_t1, const float* __restrict__ b_t1,
    const float* __restrict__ w_t2, const float* __restrict__ b_t2,
    const float* __restrict__ w_t3, const float* __restrict__ b_t3,
    float* __restrict__ ws) {
  const int b = blockIdx.x;          // 0..7
  const int tid = threadIdx.x;       // h = tid>>4, i = tid&15
  __shared__ float aQ[256], bQ[256], aK[256], bK[256], aV[256], bV[256];
  __shared__ float rks[256], kAs[256], kBs[256], stos[256];
  __shared__ float Ms[2048];         // [8 blk][256] reduced Gram
  __shared__ float Ss[512];          // [4 kind][128 ch] reduced moments

  // Phase B0: reduce 16-ps partials for this batch
#pragma unroll
  for (int blk = 0; blk < 8; ++blk) {
    const float* mp = ws + OFF_MPART + (size_t)((b * 8 + blk) * 16) * 256 + tid;
    float s = 0.f;
#pragma unroll
    for (int ps = 0; ps < 16; ++ps) s += mp[ps * 256];
    Ms[blk * 256 + tid] = s;
  }
#pragma unroll
  for (int k2 = 0; k2 < 2; ++k2) {
    const int idx = k2 * 256 + tid;    // 0..511
    const int kind = idx >> 7, ch = idx & 127;
    const float* sp = ws + OFF_SPART + (size_t)kind * 16384
                    + (size_t)(b * C_ + ch) * 16;
    float s = 0.f;
#pragma unroll
    for (int ps = 0; ps < 16; ++ps) s += sp[ps];
    Ss[idx] = s;
  }

  // Phase A: coefficient folding
  if (tid < 128) {
    const int g = tid;
    float A1[4], B1[4], A2[2], B2[2];
#pragma unroll
    for (int j = 0; j < 4; ++j) { A1[j] = w_r1[g * 4 + j]; B1[j] = b_r1[g * 4 + j]; }
#pragma unroll
    for (int i = 0; i < 2; ++i) {
      A2[i] = 0.f; B2[i] = b_r2[g * 2 + i];
#pragma unroll
      for (int j = 0; j < 4; ++j) {
        const float w = w_r2[(g * 2 + i) * 4 + j];
        A2[i] = fmaf(w, A1[j], A2[i]); B2[i] = fmaf(w, B1[j], B2[i]);
      }
    }
#pragma unroll
    for (int o = 0; o < 2; ++o) {
      float a = 0.f, bb = b_r3[g * 2 + o];
#pragma unroll
      for (int i = 0; i < 2; ++i) {
        const float w = w_r3[(g * 2 + o) * 2 + i];
        a = fmaf(w, A2[i], a); bb = fmaf(w, B2[i], bb);
      }
      aQ[g * 2 + o] = a; bQ[g * 2 + o] = bb;
    }
#pragma unroll
    for (int j = 0; j < 4; ++j) { A1[j] = w_t1[g * 4 + j]; B1[j] = b_t1[g * 4 + j]; }
#pragma unroll
    for (int i = 0; i < 2; ++i) {
      A2[i] = 0.f; B2[i] = b_t2[g * 2 + i];
#pragma unroll
      for (int j = 0; j < 4; ++j) {
        const float w = w_t2[(g * 2 + i) * 4 + j];
        A2[i] = fmaf(w, A1[j], A2[i]); B2[i] = fmaf(w, B1[j], B2[i]);
      }
    }
#pragma unroll
    for (int o = 0; o < 4; ++o) {
      float a = 0.f, bb = b_t3[g * 4 + o];
#pragma unroll
      for (int i = 0; i < 2; ++i) {
        const float w = w_t3[(g * 4 + o) * 2 + i];
        a = fmaf(w, A2[i], a); bb = fmaf(w, B2[i], bb);
      }
      if (o < 2) { aK[g * 2 + o] = a; bK[g * 2 + o] = bb; }
      else       { aV[g * 2 + (o - 2)] = a; bV[g * 2 + (o - 2)] = bb; }
    }
  }
  __syncthreads();

  const float* Sx  = Ss;
  const float* Sxx = Ss + 128;
  const float* Sto = Ss + 256;
  const float* Stt = Ss + 384;

  {
    const int h = tid >> 4, e = h >> 3, blk = h & 7, c0 = blk * 16;
    const int g = c0 + (tid & 15);
    const float a = aK[g * 2 + e], bb = bK[g * 2 + e];
    const float s2 = a * a * Stt[g] + 2.f * a * bb * Sto[g] + bb * bb * 16384.f;
    rks[tid] = 1.f / fmaxf(sqrtf(fmaxf(s2, 0.f)), 1e-12f);
    kAs[tid] = a; kBs[tid] = bb;
    stos[tid] = Sto[g];
  }
  __syncthreads();

  {
    const int h = tid >> 4, i = tid & 15, e = h >> 3, blk = h & 7, c0 = blk * 16;
    const int gi = c0 + i;
    const float gA = aQ[gi * 2 + e], gB = bQ[gi * 2 + e];
    const float sxi = Sx[gi];
    const float q2 = gA * gA * Sxx[gi] + 2.f * gA * gB * sxi + gB * gB * 16384.f;
    const float rnq = 1.f / fmaxf(sqrtf(fmaxf(q2, 0.f)), 1e-12f);
    const float tt = t[h];
    const float* Mrow = Ms + blk * 256 + i * 16;

    float lg[16];
    float mx = -1e30f;
#pragma unroll
    for (int j = 0; j < 16; ++j) {
      const float s = gA * kAs[h * 16 + j] * Mrow[j]
                    + gA * kBs[h * 16 + j] * sxi
                    + gB * kAs[h * 16 + j] * stos[h * 16 + j]
                    + gB * kBs[h * 16 + j] * 16384.f;
      const float l = tt * s * rnq * rks[h * 16 + j];
      lg[j] = l;
      mx = fmaxf(mx, l);
    }
    float den = 0.f;
#pragma unroll
    for (int j = 0; j < 16; ++j) { const float ev = expf(lg[j] - mx); lg[j] = ev; den += ev; }
    const float inv = 1.f / den;
    float cs = 0.f;
    float* WVp = ws + OFF_WV + (size_t)(b * 16 + h) * 256 + i * 16;
#pragma unroll
    for (int j = 0; j < 16; ++j) {
      const float aa = lg[j] * inv;
      const int gj = c0 + j;
      WVp[j] = aa * aV[gj * 2 + e];
      cs = fmaf(aa, bV[gj * 2 + e], cs);
    }
    ws[OFF_CST + b * 256 + i * 16 + h] = cs;
  }
}

// K3: fold attention into per-batch bf16 conv weights + constant taps.
__global__ __launch_bounds__(128) void k_weff(const float* __restrict__ w_f,
                                              float* __restrict__ ws) {
  const int b = blockIdx.x >> 7, oc = blockIdx.x & 127;
  const int c = threadIdx.x, blk = c >> 4, j = c & 15;
  const float* WVb = ws + OFF_WV;
  float acc[9];
#pragma unroll
  for (int k = 0; k < 9; ++k) acc[k] = 0.f;
#pragma unroll
  for (int e = 0; e < 2; ++e) {
    const int h = e * 8 + blk;
#pragma unroll
    for (int i = 0; i < 16; ++i) {
      const float coef = WVb[((size_t)(b * 16 + h) * 16 + i) * 16 + j];
      const float* wf = w_f + (size_t)(oc * 256 + i * 16 + h) * 9;
#pragma unroll
      for (int k = 0; k < 9; ++k) acc[k] = fmaf(wf[k], coef, acc[k]);
    }
  }
  unsigned short* wb16 = (unsigned short*)(ws + OFF_WEFF);
#pragma unroll
  for (int k = 0; k < 9; ++k)
    wb16[(((size_t)(b * 9 + k)) * 128 + oc) * 128 + c] = f2bf(acc[k]);

  __shared__ float tp[9][128];
  float tl[9];
#pragma unroll
  for (int k = 0; k < 9; ++k) tl[k] = 0.f;
  const float* cst = ws + OFF_CST + b * 256;
  for (int cc = c; cc < 256; cc += 128) {
    const float cv = cst[cc];
    const float* wf = w_f + (size_t)(oc * 256 + cc) * 9;
#pragma unroll
    for (int k = 0; k < 9; ++k) tl[k] = fmaf(wf[k], cv, tl[k]);
  }
#pragma unroll
  for (int k = 0; k < 9; ++k) tp[k][c] = tl[k];
  __syncthreads();
  for (int s = 64; s > 0; s >>= 1) {
    if (c < s) {
#pragma unroll
      for (int k = 0; k < 9; ++k) tp[k][c] += tp[k][c + s];
    }
    __syncthreads();
  }
  if (c < 9) ws[OFF_T + ((size_t)b * 128 + oc) * 9 + c] = tp[c][0];
}

// K4 (R10/R15 best-measured version): m97-style double-buffered gload_lds
// conv-GEMM. Block = (b, y): 128 oc x 128 px, 18 steps (9 taps x 2 cin-halves).
// LDS: A[2][128][64] + B[2][128][64] bf16 = 64 KiB -> 2 blocks/CU.
__global__ __launch_bounds__(512, 4) void k_conv(const float* __restrict__ xin,
                                                 const float* __restrict__ b_f,
                                                 const float* __restrict__ ws,
                                                 const unsigned short* __restrict__ t2,
                                                 float* __restrict__ out) {
  const int d = blockIdx.x;           // 1024 = b(8, fast -> XCD) * y(128)
  const int b = d & 7;
  const int y = d >> 3;
  const int tid = threadIdx.x;

  __shared__ unsigned short As[2][128 * 64];
  __shared__ unsigned short Bs[2][128 * 64];

  const unsigned short* wb = (const unsigned short*)(ws + OFF_WEFF)
      + (size_t)b * 9 * 16384;
  const unsigned short* t2y = t2 + (size_t)b * T2_BATCH + (size_t)y * T2_ROW;

  const int l = tid & 63;
  const int lm = l & 15, lh = l >> 4;
  const int wv = tid >> 6;
  const int oc0w = (wv >> 1) * 32;    // 4 wave-rows of 32 oc
  const int px0w = (wv & 1) * 64;     // 2 wave-cols of 64 px

  const int trow0 = tid >> 3, tci0 = tid & 7;
  const unsigned udst0 = (unsigned)((tid & ~63) * 16);
  const unsigned udst1 = udst0 + 512u * 16u;

#define STAGE(BUF, S)                                                          \
  {                                                                            \
    const int tap_ = (S) >> 1, ks_ = (S) & 1;                                  \
    const int dy_ = tap_ / 3, dx_ = tap_ - dy_ * 3;                            \
    const unsigned short* asrc = wb + (size_t)tap_ * 16384 + ks_ * 64;         \
    const unsigned short* bsrc = t2y + (size_t)dy_ * T2_ROW + dx_ * 128 + ks_ * 64; \
    gl16(asrc + (size_t)trow0 * 128 + ((tci0 ^ (trow0 & 7)) << 3),             \
         (char*)&As[BUF][0] + udst0);                                          \
    gl16(asrc + (size_t)(trow0 + 64) * 128 + ((tci0 ^ ((trow0 + 64) & 7)) << 3), \
         (char*)&As[BUF][0] + udst1);                                          \
    gl16(bsrc + (size_t)trow0 * 128 + ((tci0 ^ (trow0 & 7)) << 3),             \
         (char*)&Bs[BUF][0] + udst0);                                          \
    gl16(bsrc + (size_t)(trow0 + 64) * 128 + ((tci0 ^ ((trow0 + 64) & 7)) << 3), \
         (char*)&Bs[BUF][0] + udst1);                                          \
  }

  f32x4 acc[2][4];
#pragma unroll
  for (int mt = 0; mt < 2; ++mt)
#pragma unroll
    for (int nt = 0; nt < 4; ++nt) acc[mt][nt] = (f32x4)0.f;

  STAGE(0, 0);
  __syncthreads();   // drains vmcnt -> buf0 ready

  int cur = 0;
#pragma unroll 1
  for (int s = 0; s < 18; ++s) {
    if (s + 1 < 18) STAGE(cur ^ 1, s + 1);   // async prefetch under MFMAs

    const char* Ab = (const char*)&As[cur][0];
    const char* Bb = (const char*)&Bs[cur][0];
#pragma unroll
    for (int ki = 0; ki < 2; ++ki) {
      short8 af[2], bfr[4];
#pragma unroll
      for (int mt = 0; mt < 2; ++mt) {
        const int oc = oc0w + mt * 16 + lm;
        af[mt] = *(const short8*)(Ab + oc * 128 + (((ki * 4 + lh) ^ (oc & 7)) << 4));
      }
#pragma unroll
      for (int nt = 0; nt < 4; ++nt) {
        const int px = px0w + nt * 16 + lm;
        bfr[nt] = *(const short8*)(Bb + px * 128 + (((ki * 4 + lh) ^ (px & 7)) << 4));
      }
#pragma unroll
      for (int mt = 0; mt < 2; ++mt) {
        acc[mt][0] = mfma16(af[mt], bfr[0], acc[mt][0]);
        acc[mt][1] = mfma16(af[mt], bfr[1], acc[mt][1]);
        acc[mt][2] = mfma16(af[mt], bfr[2], acc[mt][2]);
        acc[mt][3] = mfma16(af[mt], bfr[3], acc[mt][3]);
      }
    }
    __syncthreads();   // waits prefetch (vmcnt) + protects buf overwrite
    cur ^= 1;
  }
#undef STAGE

  // epilogue: per-oc constant terms (reuse As as f32 scratch)
  float* sm = (float*)&As[0][0];   // [3][128]: add, left, right
  if (tid < 128) {
    const float* Tk = ws + OFF_T + (size_t)(b * 128 + tid) * 9;
    float s = Tk[3] + Tk[4] + Tk[5], sl = Tk[3], sr = Tk[5];
    if (y >= 1)   { s += Tk[0] + Tk[1] + Tk[2]; sl += Tk[0]; sr += Tk[2]; }
    if (y <= 126) { s += Tk[6] + Tk[7] + Tk[8]; sl += Tk[6]; sr += Tk[8]; }
    sm[tid] = s + b_f[tid]; sm[128 + tid] = sl; sm[256 + tid] = sr;
  }
  __syncthreads();

#pragma unroll
  for (int mt = 0; mt < 2; ++mt)
#pragma unroll
    for (int nt = 0; nt < 4; ++nt) {
      const int px = px0w + nt * 16 + lm;
#pragma unroll
      for (int r = 0; r < 4; ++r) {
        const int oc = oc0w + mt * 16 + lh * 4 + r;
        float add = sm[oc];
        if (px == 0)   add -= sm[128 + oc];
        if (px == 127) add -= sm[256 + oc];
        const float z = acc[mt][nt][r] + add;
        const size_t base = ((size_t)(b * C_ + oc)) * HW_ + (size_t)y * W_ + px;
        const float rx = xin[base];
        out[base] = rx + (z >= 0.f ? z : 0.2f * z);
      }
    }
}

// K4 fallback (R2 version): used when ws_size can't hold T2.
__global__ __launch_bounds__(512, 4) void k_conv_fb(const float* __restrict__ xin,
                                                    const float* __restrict__ to,
                                                    const float* __restrict__ b_f,
                                                    const float* __restrict__ ws,
                                                    float* __restrict__ out) {
  const int bid = blockIdx.x;
  const int nb  = (bid & 7) * 128 + (bid >> 3);
  const int b   = nb >> 7;
  const int y   = nb & 127;
  const int tid = threadIdx.x;

  __shared__ f32x4 ldsbuf[3120];
  char* lp = (char*)ldsbuf;

  f32x4 acc[4][2];
#pragma unroll
  for (int mt = 0; mt < 4; ++mt)
#pragma unroll
    for (int nt = 0; nt < 2; ++nt) acc[mt][nt] = (f32x4)0.f;

  const float* tob = to + (size_t)b * C_ * HW_;
  const unsigned short* wb16 =
      (const unsigned short*)(ws + OFF_WEFF) + (size_t)b * 9 * 128 * 128;

  const int l = tid & 63, wv = tid >> 6;
  const int ocb0 = (wv & 1) * 64, pxb0 = (wv >> 1) * 32;
  const int lm = l & 15, lh = l >> 4;

  for (int cb = 0; cb < 128; cb += 64) {
    __syncthreads();
    {
      const int xg = tid & 31, cq = (tid >> 5) & 15;
      const int cbase = cb + cq * 4;
#pragma unroll
      for (int row = 0; row < 3; ++row) {
        const int y_in = y + row - 1;
        const bool yok = ((unsigned)y_in < 128u);
        const float* src = tob + (size_t)cbase * HW_ + (size_t)y_in * W_;
#pragma unroll
        for (int xb = 0; xb < 5; ++xb) {
          const int xi = xb * 32 + xg;
          if (xi < 130) {
            const int x_in = xi - 1;
            const bool ok = yok && ((unsigned)x_in < 128u);
            float f0 = 0.f, f1 = 0.f, f2 = 0.f, f3 = 0.f;
            if (ok) {
              f0 = src[x_in];
              f1 = src[HW_ + x_in];
              f2 = src[2 * HW_ + x_in];
              f3 = src[3 * HW_ + x_in];
            }
            ushort4 pk;
            pk.x = f2bf(f0); pk.y = f2bf(f1); pk.z = f2bf(f2); pk.w = f2bf(f3);
            const int boff = (row * 130 + xi) * 128 + ((cq * 8) ^ ((xi & 7) << 4));
            *(ushort4*)(lp + boff) = pk;
          }
        }
      }
    }
    __syncthreads();

    for (int tap = 0; tap < 9; ++tap) {
      const int dy = tap / 3, dx = tap - dy * 3;
#pragma unroll
      for (int ks = 0; ks < 2; ++ks) {
        short8 bfr[2];
#pragma unroll
        for (int nt = 0; nt < 2; ++nt) {
          const int xi = pxb0 + nt * 16 + lm + dx;
          const int boff = (dy * 130 + xi) * 128 + ((ks * 64 + lh * 16) ^ ((xi & 7) << 4));
          bfr[nt] = *(const short8*)(lp + boff);
        }
        const int cin = cb + ks * 32 + lh * 8;
#pragma unroll
        for (int mt = 0; mt < 4; ++mt) {
          const int oc = ocb0 + mt * 16 + lm;
          const short8 af = *(const short8*)(wb16 + ((size_t)tap * 128 + oc) * 128 + cin);
          acc[mt][0] = mfma16(af, bfr[0], acc[mt][0]);
          acc[mt][1] = mfma16(af, bfr[1], acc[mt][1]);
        }
      }
    }
  }

  __syncthreads();
  float* sAdd = (float*)ldsbuf;
  float* sLft = sAdd + 128;
  float* sRgt = sAdd + 256;
  if (tid < 128) {
    const float* Tk = ws + OFF_T + (size_t)(b * 128 + tid) * 9;
    float s = Tk[3] + Tk[4] + Tk[5], sl = Tk[3], sr = Tk[5];
    if (y >= 1)   { s += Tk[0] + Tk[1] + Tk[2]; sl += Tk[0]; sr += Tk[2]; }
    if (y <= 126) { s += Tk[6] + Tk[7] + Tk[8]; sl += Tk[6]; sr += Tk[8]; }
    sAdd[tid] = s + b_f[tid]; sLft[tid] = sl; sRgt[tid] = sr;
  }
  __syncthreads();

#pragma unroll
  for (int mt = 0; mt < 4; ++mt)
#pragma unroll
    for (int nt = 0; nt < 2; ++nt) {
      const int px = pxb0 + nt * 16 + lm;
#pragma unroll
      for (int r = 0; r < 4; ++r) {
        const int oc = ocb0 + mt * 16 + lh * 4 + r;
        float add = sAdd[oc];
        if (px == 0)   add -= sLft[oc];
        if (px == 127) add -= sRgt[oc];
        const float z = acc[mt][nt][r] + add;
        const size_t base = ((size_t)(b * C_ + oc)) * HW_ + (size_t)y * W_ + px;
        const float rx = xin[base];
        out[base] = rx + (z >= 0.f ? z : 0.2f * z);
      }
    }
}

extern "C" void kernel_launch(void* const* d_in, const int* in_sizes, int n_in,
                              void* d_out, int out_size, void* d_ws, size_t ws_size,
                              hipStream_t stream) {
  (void)in_sizes; (void)n_in; (void)out_size;
  const float* x    = (const float*)d_in[0];
  const float* to   = (const float*)d_in[1];
  const float* t    = (const float*)d_in[2];
  const float* w_r1 = (const float*)d_in[3];
  const float* b_r1 = (const float*)d_in[4];
  const float* w_r2 = (const float*)d_in[5];
  const float* b_r2 = (const float*)d_in[6];
  const float* w_r3 = (const float*)d_in[7];
  const float* b_r3 = (const float*)d_in[8];
  const float* w_t1 = (const float*)d_in[9];
  const float* b_t1 = (const float*)d_in[10];
  const float* w_t2 = (const float*)d_in[11];
  const float* b_t2 = (const float*)d_in[12];
  const float* w_t3 = (const float*)d_in[13];
  const float* b_t3 = (const float*)d_in[14];
  const float* w_f  = (const float*)d_in[15];
  const float* b_f  = (const float*)d_in[16];
  float* ws  = (float*)d_ws;
  float* out = (float*)d_out;
  unsigned short* t2 = (unsigned short*)(ws + OFF_T2F);
  const bool fast = (ws_size >= WS_NEED);

  k_gram<<<1024, 256, 0, stream>>>(x, to, ws);
  if (fast) k_trz<<<2064, 256, 0, stream>>>(to, t2);
  k_attn<<<8, 256, 0, stream>>>(t, w_r1, b_r1, w_r2, b_r2, w_r3, b_r3,
                                w_t1, b_t1, w_t2, b_t2, w_t3, b_t3, ws);
  k_weff<<<1024, 128, 0, stream>>>(w_f, ws);
  if (fast) k_conv<<<1024, 512, 0, stream>>>(x, b_f, ws, t2, out);
  else      k_conv_fb<<<1024, 512, 0, stream>>>(x, to, b_f, ws, out);
}

// Round 20
// 111.340 us; speedup vs baseline: 1.0819x; 1.0043x over previous
//
#include <hip/hip_runtime.h>
#include <math.h>

#define B_  8
#define C_  128
#define H_  128
#define W_  128
#define HW_ 16384

// ---- workspace layout (float offsets) ----
#define OFF_MPART 0          // [64 bblk][16 ps][256]     = 262144
#define OFF_SPART 262144     // [4 kind][1024 bc][16 ps]  = 65536
#define OFF_WV    348160     // [8][16][16][16]           = 32768
#define OFF_CST   380928     // [8][256]                  = 2048
#define OFF_T     382976     // [8][128][9]               = 9216
#define OFF_WEFF  392192     // bf16 [8][9 tap][128 oc][128 cin] = 1179648 ushort = 589824 fl
#define OFF_T2F   982016     // bf16 T2 [8][130 y'][130 x'][128 c] = 17305600 ushort
#define T2_ROW    16640      // 130*128 shorts
#define T2_BATCH  2163200    // 130*16640 shorts
#define WS_NEED   (982016ull * 4ull + 34611200ull)

typedef __attribute__((ext_vector_type(8))) short short8;
typedef __attribute__((ext_vector_type(4))) float f32x4;

__device__ __forceinline__ unsigned short f2bf(float f) {
  unsigned u = __float_as_uint(f);
  u += 0x7fffu + ((u >> 16) & 1u);
  return (unsigned short)(u >> 16);
}

__device__ __forceinline__ f32x4 mfma16(short8 a, short8 b, f32x4 c) {
  return __builtin_amdgcn_mfma_f32_16x16x32_bf16(a, b, c, 0, 0, 0);
}

// async global->LDS 16B: HW dest = wave-uniform base + lane*16
__device__ __forceinline__ void gl16(const void* g, void* l) {
  const unsigned loff = (unsigned)(unsigned long long)l;
  __builtin_amdgcn_global_load_lds(
      (const __attribute__((address_space(1))) void*)g,
      (__attribute__((address_space(3))) void*)loff, 16, 0, 0);
}

// K1 (MFMA Gram): grid = b(8) x blk(8) x ps(16).
__global__ __launch_bounds__(256) void k_gram(const float* __restrict__ x,
                                              const float* __restrict__ to,
                                              float* __restrict__ ws) {
  const int bid = blockIdx.x;       // 0..1023
  const int ps  = bid & 15;
  const int blk = (bid >> 4) & 7;
  const int b   = bid >> 7;
  const int tid = threadIdx.x;
  const int w = tid >> 6, l = tid & 63;
  const int lm = l & 15, lh = l >> 4;
  const int c0 = blk * 16;

  const float* xc = x  + ((size_t)b * C_ + c0 + lm) * HW_;
  const float* tc = to + ((size_t)b * C_ + c0 + lm) * HW_;
  const int p0 = ps * 1024 + w * 256 + lh * 8;

  f32x4 acc = (f32x4)0.f;
  float sx = 0.f, sxx = 0.f, st = 0.f, stt = 0.f;
#pragma unroll
  for (int it = 0; it < 8; ++it) {
    const int p = p0 + it * 32;
    const f32x4 xa = *(const f32x4*)(xc + p);
    const f32x4 xb = *(const f32x4*)(xc + p + 4);
    const f32x4 ta = *(const f32x4*)(tc + p);
    const f32x4 tb = *(const f32x4*)(tc + p + 4);
    short8 xf, tf;
#pragma unroll
    for (int e = 0; e < 4; ++e) {
      xf[e]     = (short)f2bf(xa[e]);
      xf[4 + e] = (short)f2bf(xb[e]);
      tf[e]     = (short)f2bf(ta[e]);
      tf[4 + e] = (short)f2bf(tb[e]);
      sx += xa[e] + xb[e];
      sxx = fmaf(xa[e], xa[e], fmaf(xb[e], xb[e], sxx));
      st += ta[e] + tb[e];
      stt = fmaf(ta[e], ta[e], fmaf(tb[e], tb[e], stt));
    }
    acc = mfma16(xf, tf, acc);   // D[m=x-ch][n=to-ch]
  }

  sx  += __shfl_xor(sx, 16);  sx  += __shfl_xor(sx, 32);
  sxx += __shfl_xor(sxx, 16); sxx += __shfl_xor(sxx, 32);
  st  += __shfl_xor(st, 16);  st  += __shfl_xor(st, 32);
  stt += __shfl_xor(stt, 16); stt += __shfl_xor(stt, 32);

  __shared__ float smM[4][256];
  __shared__ float smS[4][4][16];
#pragma unroll
  for (int r = 0; r < 4; ++r)
    smM[w][(lh * 4 + r) * 16 + lm] = acc[r];   // row=(l>>4)*4+r, col=l&15 (m89)
  if (l < 16) {
    smS[w][0][lm] = sx;  smS[w][1][lm] = sxx;
    smS[w][2][lm] = st;  smS[w][3][lm] = stt;
  }
  __syncthreads();

  {
    const float s = smM[0][tid & 255] + smM[1][tid & 255]
                  + smM[2][tid & 255] + smM[3][tid & 255];
    ws[OFF_MPART + (size_t)((b * 8 + blk) * 16 + ps) * 256 + tid] = s;
  }
  if (tid < 64) {
    const int kind = tid >> 4, ch = tid & 15;
    const float s = smS[0][kind][ch] + smS[1][kind][ch]
                  + smS[2][kind][ch] + smS[3][kind][ch];
    ws[OFF_SPART + (size_t)kind * 16384 + (size_t)(b * C_ + c0 + ch) * 16 + ps] = s;
  }
}

// K_trz: transpose to -> bf16 T2[b][y'][x'][c] (blocks 0..2047), plus border
// zero rows y'=0/129 (blocks 2048..2063). Fused k_tr + k_zero.
__global__ __launch_bounds__(256) void k_trz(const float* __restrict__ to,
                                             unsigned short* __restrict__ t2) {
  const int d  = blockIdx.x;
  const int tid = threadIdx.x;
  if (d >= 2048) {
    const int e = d - 2048;          // 0..15: b(8) x r(2)
    const int b = e >> 1, r = e & 1;
    unsigned short* row = t2 + (size_t)b * T2_BATCH + (size_t)(r ? 129 : 0) * T2_ROW;
    const short8 z = {0,0,0,0,0,0,0,0};
    for (int idx = tid; idx < 2080; idx += 256)
      *(short8*)(row + (size_t)idx * 8) = z;
    return;
  }
  const int xh = d & 1;
  const int y  = (d >> 1) & 127;
  const int b  = d >> 8;
  __shared__ char lds[64 * 256];      // 16 KB

  const int x0 = xh * 64;
  const int xq = tid & 15;            // x-quad
  const int cg = tid >> 4;            // channel group
  const float* srcb = to + ((size_t)b * C_ + cg * 8) * HW_ + (size_t)y * W_ + x0 + xq * 4;
#pragma unroll
  for (int k = 0; k < 8; ++k) {
    const f32x4 v = *(const f32x4*)(srcb + (size_t)k * HW_);
    const int c = cg * 8 + k;
#pragma unroll
    for (int e = 0; e < 4; ++e) {
      const int xl = xq * 4 + e;
      const int boff = xl * 256 + ((2 * c) ^ ((xl & 7) << 4));
      *(unsigned short*)(lds + boff) = f2bf(v[e]);
    }
  }
  __syncthreads();

  unsigned short* rowbase = t2 + (size_t)b * T2_BATCH + (size_t)(y + 1) * T2_ROW;
#pragma unroll
  for (int i = 0; i < 4; ++i) {
    const int xx = tid >> 2;
    const int cs = (tid & 3) + i * 4;   // 0..15
    short8 val = *(short8*)(lds + xx * 256 + ((cs * 16) ^ ((xx & 7) << 4)));
    *(short8*)(rowbase + (size_t)(x0 + xx + 1) * 128 + cs * 8) = val;
  }
  if (tid < 16) {
    short8 z = {0,0,0,0,0,0,0,0};
    if (xh == 0) *(short8*)(rowbase + tid * 8) = z;
    else         *(short8*)(rowbase + (size_t)129 * 128 + tid * 8) = z;
  }
}

// K2 (fused redB+attn): one block per batch.
__global__ __launch_bounds__(256) void k_attn(const float* __restrict__ t,
    const float* __restrict__ w_r1, const float* __restrict__ b_r1,
    const float* __restrict__ w_r2, const float* __restrict__ b_r2,
    const float* __restrict__ w_r3, const float* __restrict__ b_r3,
    const float* __restrict__ w_t1, const float* __restrict__ b_t1,
    const float* __restrict__ w_t2, const float* __restrict__ b_t2,
    const float* __restrict__ w_t3, const float* __restrict__ b_t3,
    float* __restrict__ ws) {
  const int b = blockIdx.x;          // 0..7
  const int tid = threadIdx.x;       // h = tid>>4, i = tid&15
  __shared__ float aQ[256], bQ[256], aK[256], bK[256], aV[256], bV[256];
  __shared__ float rks[256], kAs[256], kBs[256], stos[256];
  __shared__ float Ms[2048];         // [8 blk][256] reduced Gram
  __shared__ float Ss[512];          // [4 kind][128 ch] reduced moments

#pragma unroll
  for (int blk = 0; blk < 8; ++blk) {
    const float* mp = ws + OFF_MPART + (size_t)((b * 8 + blk) * 16) * 256 + tid;
    float s = 0.f;
#pragma unroll
    for (int ps = 0; ps < 16; ++ps) s += mp[ps * 256];
    Ms[blk * 256 + tid] = s;
  }
#pragma unroll
  for (int k2 = 0; k2 < 2; ++k2) {
    const int idx = k2 * 256 + tid;    // 0..511
    const int kind = idx >> 7, ch = idx & 127;
    const float* sp = ws + OFF_SPART + (size_t)kind * 16384
                    + (size_t)(b * C_ + ch) * 16;
    float s = 0.f;
#pragma unroll
    for (int ps = 0; ps < 16; ++ps) s += sp[ps];
    Ss[idx] = s;
  }

  if (tid < 128) {
    const int g = tid;
    float A1[4], B1[4], A2[2], B2[2];
#pragma unroll
    for (int j = 0; j < 4; ++j) { A1[j] = w_r1[g * 4 + j]; B1[j] = b_r1[g * 4 + j]; }
#pragma unroll
    for (int i = 0; i < 2; ++i) {
      A2[i] = 0.f; B2[i] = b_r2[g * 2 + i];
#pragma unroll
      for (int j = 0; j < 4; ++j) {
        const float w = w_r2[(g * 2 + i) * 4 + j];
        A2[i] = fmaf(w, A1[j], A2[i]); B2[i] = fmaf(w, B1[j], B2[i]);
      }
    }
#pragma unroll
    for (int o = 0; o < 2; ++o) {
      float a = 0.f, bb = b_r3[g * 2 + o];
#pragma unroll
      for (int i = 0; i < 2; ++i) {
        const float w = w_r3[(g * 2 + o) * 2 + i];
        a = fmaf(w, A2[i], a); bb = fmaf(w, B2[i], bb);
      }
      aQ[g * 2 + o] = a; bQ[g * 2 + o] = bb;
    }
#pragma unroll
    for (int j = 0; j < 4; ++j) { A1[j] = w_t1[g * 4 + j]; B1[j] = b_t1[g * 4 + j]; }
#pragma unroll
    for (int i = 0; i < 2; ++i) {
      A2[i] = 0.f; B2[i] = b_t2[g * 2 + i];
#pragma unroll
      for (int j = 0; j < 4; ++j) {
        const float w = w_t2[(g * 2 + i) * 4 + j];
        A2[i] = fmaf(w, A1[j], A2[i]); B2[i] = fmaf(w, B1[j], B2[i]);
      }
    }
#pragma unroll
    for (int o = 0; o < 4; ++o) {
      float a = 0.f, bb = b_t3[g * 4 + o];
#pragma unroll
      for (int i = 0; i < 2; ++i) {
        const float w = w_t3[(g * 4 + o) * 2 + i];
        a = fmaf(w, A2[i], a); bb = fmaf(w, B2[i], bb);
      }
      if (o < 2) { aK[g * 2 + o] = a; bK[g * 2 + o] = bb; }
      else       { aV[g * 2 + (o - 2)] = a; bV[g * 2 + (o - 2)] = bb; }
    }
  }
  __syncthreads();

  const float* Sx  = Ss;
  const float* Sxx = Ss + 128;
  const float* Sto = Ss + 256;
  const float* Stt = Ss + 384;

  {
    const int h = tid >> 4, e = h >> 3, blk = h & 7, c0 = blk * 16;
    const int g = c0 + (tid & 15);
    const float a = aK[g * 2 + e], bb = bK[g * 2 + e];
    const float s2 = a * a * Stt[g] + 2.f * a * bb * Sto[g] + bb * bb * 16384.f;
    rks[tid] = 1.f / fmaxf(sqrtf(fmaxf(s2, 0.f)), 1e-12f);
    kAs[tid] = a; kBs[tid] = bb;
    stos[tid] = Sto[g];
  }
  __syncthreads();

  {
    const int h = tid >> 4, i = tid & 15, e = h >> 3, blk = h & 7, c0 = blk * 16;
    const int gi = c0 + i;
    const float gA = aQ[gi * 2 + e], gB = bQ[gi * 2 + e];
    const float sxi = Sx[gi];
    const float q2 = gA * gA * Sxx[gi] + 2.f * gA * gB * sxi + gB * gB * 16384.f;
    const float rnq = 1.f / fmaxf(sqrtf(fmaxf(q2, 0.f)), 1e-12f);
    const float tt = t[h];
    const float* Mrow = Ms + blk * 256 + i * 16;

    float lg[16];
    float mx = -1e30f;
#pragma unroll
    for (int j = 0; j < 16; ++j) {
      const float s = gA * kAs[h * 16 + j] * Mrow[j]
                    + gA * kBs[h * 16 + j] * sxi
                    + gB * kAs[h * 16 + j] * stos[h * 16 + j]
                    + gB * kBs[h * 16 + j] * 16384.f;
      const float l = tt * s * rnq * rks[h * 16 + j];
      lg[j] = l;
      mx = fmaxf(mx, l);
    }
    float den = 0.f;
#pragma unroll
    for (int j = 0; j < 16; ++j) { const float ev = expf(lg[j] - mx); lg[j] = ev; den += ev; }
    const float inv = 1.f / den;
    float cs = 0.f;
    float* WVp = ws + OFF_WV + (size_t)(b * 16 + h) * 256 + i * 16;
#pragma unroll
    for (int j = 0; j < 16; ++j) {
      const float aa = lg[j] * inv;
      const int gj = c0 + j;
      WVp[j] = aa * aV[gj * 2 + e];
      cs = fmaf(aa, bV[gj * 2 + e], cs);
    }
    ws[OFF_CST + b * 256 + i * 16 + h] = cs;
  }
}

// K3: fold attention into per-batch bf16 conv weights + constant taps.
__global__ __launch_bounds__(128) void k_weff(const float* __restrict__ w_f,
                                              float* __restrict__ ws) {
  const int b = blockIdx.x >> 7, oc = blockIdx.x & 127;
  const int c = threadIdx.x, blk = c >> 4, j = c & 15;
  const float* WVb = ws + OFF_WV;
  float acc[9];
#pragma unroll
  for (int k = 0; k < 9; ++k) acc[k] = 0.f;
#pragma unroll
  for (int e = 0; e < 2; ++e) {
    const int h = e * 8 + blk;
#pragma unroll
    for (int i = 0; i < 16; ++i) {
      const float coef = WVb[((size_t)(b * 16 + h) * 16 + i) * 16 + j];
      const float* wf = w_f + (size_t)(oc * 256 + i * 16 + h) * 9;
#pragma unroll
      for (int k = 0; k < 9; ++k) acc[k] = fmaf(wf[k], coef, acc[k]);
    }
  }
  unsigned short* wb16 = (unsigned short*)(ws + OFF_WEFF);
#pragma unroll
  for (int k = 0; k < 9; ++k)
    wb16[(((size_t)(b * 9 + k)) * 128 + oc) * 128 + c] = f2bf(acc[k]);

  __shared__ float tp[9][128];
  float tl[9];
#pragma unroll
  for (int k = 0; k < 9; ++k) tl[k] = 0.f;
  const float* cst = ws + OFF_CST + b * 256;
  for (int cc = c; cc < 256; cc += 128) {
    const float cv = cst[cc];
    const float* wf = w_f + (size_t)(oc * 256 + cc) * 9;
#pragma unroll
    for (int k = 0; k < 9; ++k) tl[k] = fmaf(wf[k], cv, tl[k]);
  }
#pragma unroll
  for (int k = 0; k < 9; ++k) tp[k][c] = tl[k];
  __syncthreads();
  for (int s = 64; s > 0; s >>= 1) {
    if (c < s) {
#pragma unroll
      for (int k = 0; k < 9; ++k) tp[k][c] += tp[k][c + s];
    }
    __syncthreads();
  }
  if (c < 9) ws[OFF_T + ((size_t)b * 128 + oc) * 9 + c] = tp[c][0];
}

// K4: low-traffic 2-row x-half block at 2 blocks/CU.
// Block = (b, xh, y-pair): 128 oc x 64 px x 2 rows. 8 waves: (row, oc-half,
// px-half), wave tile 64 oc x 32 px. Per ks: B4[4 rows][66 x][64 cin] staged
// ONCE (33 KB); A[2][128][64] dbuf per tap (16 KB steps). LDS 65 KB.
// Staged per block: 288 KB (A) + 66 KB (B) = 354 KB vs 576 KB (R15 per row pair).
__global__ __launch_bounds__(512, 2) void k_conv(const float* __restrict__ xin,
                                                 const float* __restrict__ b_f,
                                                 const float* __restrict__ ws,
                                                 const unsigned short* __restrict__ t2,
                                                 float* __restrict__ out) {
  const int d  = blockIdx.x;          // 1024 = b(8, fast -> XCD) * xh(2) * y2(64)
  const int b  = d & 7;
  const int xh = (d >> 3) & 1;
  const int y2 = d >> 4;              // 0..63
  const int tid = threadIdx.x;

  __shared__ unsigned short B4s[4 * 66 * 64];   // 33,792 B
  __shared__ unsigned short As[2][128 * 64];    // 32,768 B

  const unsigned short* wb = (const unsigned short*)(ws + OFF_WEFF)
      + (size_t)b * 9 * 16384;
  const unsigned short* t2b4 = t2 + (size_t)b * T2_BATCH
      + (size_t)(y2 * 2) * T2_ROW + (size_t)(xh * 64) * 128;

  const int l = tid & 63;
  const int lm = l & 15, lh = l >> 4;
  const int wv = tid >> 6;            // 0..7
  const int rw   = wv >> 2;           // output row within pair
  const int oc0w = ((wv >> 1) & 1) * 64;
  const int px0  = (wv & 1) * 32;     // local px within the 64-px half

  const unsigned udstw = (unsigned)((tid & ~63) * 16);

  // B4: 2112 16B tasks; q -> rr = q/528, xi = (q%528)>>3, c8 = q&7
#define STAGE_B4(KS)                                                           \
  {                                                                            \
    _Pragma("unroll")                                                          \
    for (int i_ = 0; i_ < 4; ++i_) {                                           \
      const int q_ = i_ * 512 + tid;                                           \
      const int rr_ = q_ / 528;                                                \
      const int rem_ = q_ - rr_ * 528;                                         \
      const int xi_ = rem_ >> 3, c8_ = rem_ & 7;                               \
      gl16(t2b4 + (size_t)rr_ * T2_ROW + xi_ * 128 + (KS) * 64                 \
               + ((c8_ ^ (xi_ & 7)) << 3),                                     \
           (char*)B4s + (unsigned)(i_ * 8192) + udstw);                        \
    }                                                                          \
    if (tid < 64) {                                                            \
      const int q_ = 2048 + tid;                                               \
      const int rr_ = q_ / 528;                                                \
      const int rem_ = q_ - rr_ * 528;                                         \
      const int xi_ = rem_ >> 3, c8_ = rem_ & 7;                               \
      gl16(t2b4 + (size_t)rr_ * T2_ROW + xi_ * 128 + (KS) * 64                 \
               + ((c8_ ^ (xi_ & 7)) << 3),                                     \
           (char*)B4s + 32768u);                                               \
    }                                                                          \
  }

#define STAGE_A(BUF, TAP, KS)                                                  \
  {                                                                            \
    const unsigned short* asrc = wb + (size_t)(TAP) * 16384 + (KS) * 64;       \
    _Pragma("unroll")                                                          \
    for (int k_ = 0; k_ < 2; ++k_) {                                           \
      const int task_ = k_ * 512 + tid;                                        \
      const int trow_ = task_ >> 3, c8_ = task_ & 7;                           \
      gl16(asrc + (size_t)trow_ * 128 + ((c8_ ^ (trow_ & 7)) << 3),            \
           (char*)&As[BUF][0] + (unsigned)(k_ * 8192) + udstw);                \
    }                                                                          \
  }

  f32x4 acc[4][2];
#pragma unroll
  for (int mt = 0; mt < 4; ++mt) { acc[mt][0] = (f32x4)0.f; acc[mt][1] = (f32x4)0.f; }

#pragma unroll 1
  for (int ks = 0; ks < 2; ++ks) {
    STAGE_B4(ks);
    STAGE_A(0, 0, ks);
    __syncthreads();   // drains all staging

    int cur = 0;
#pragma unroll 1
    for (int tap = 0; tap < 9; ++tap) {
      if (tap + 1 < 9) STAGE_A(cur ^ 1, tap + 1, ks);   // prefetch under MFMAs

      const int dy = tap / 3, dx = tap - dy * 3;
      const int rdy = rw + dy;                    // B4 row 0..3
      const char* Ab = (const char*)&As[cur][0];
      const char* Bb = (const char*)B4s;
#pragma unroll
      for (int ki = 0; ki < 2; ++ki) {
        short8 af[4], bfr[2];
#pragma unroll
        for (int mt = 0; mt < 4; ++mt) {
          const int oc = oc0w + mt * 16 + lm;
          af[mt] = *(const short8*)(Ab + oc * 128 + (((ki * 4 + lh) ^ (oc & 7)) << 4));
        }
#pragma unroll
        for (int nt = 0; nt < 2; ++nt) {
          const int xi = px0 + nt * 16 + lm + dx;   // 0..65
          bfr[nt] = *(const short8*)(Bb + (rdy * 66 + xi) * 128
                                        + (((ki * 4 + lh) ^ (xi & 7)) << 4));
        }
#pragma unroll
        for (int mt = 0; mt < 4; ++mt) {
          acc[mt][0] = mfma16(af[mt], bfr[0], acc[mt][0]);
          acc[mt][1] = mfma16(af[mt], bfr[1], acc[mt][1]);
        }
      }
      __syncthreads();   // waits A prefetch + protects buf/B4 overwrite
      cur ^= 1;
    }
  }
#undef STAGE_A
#undef STAGE_B4

  // epilogue: per (row, oc) constant terms (reuse B4s as f32 scratch)
  float* sm = (float*)B4s;   // [2][384]: add, left, right per row
  if (tid < 256) {
    const int rr = tid >> 7, oc = tid & 127;
    const int y = y2 * 2 + rr;
    const float* Tk = ws + OFF_T + (size_t)(b * 128 + oc) * 9;
    float s = Tk[3] + Tk[4] + Tk[5], sl = Tk[3], sr = Tk[5];
    if (y >= 1)   { s += Tk[0] + Tk[1] + Tk[2]; sl += Tk[0]; sr += Tk[2]; }
    if (y <= 126) { s += Tk[6] + Tk[7] + Tk[8]; sl += Tk[6]; sr += Tk[8]; }
    sm[rr * 384 + oc] = s + b_f[oc];
    sm[rr * 384 + 128 + oc] = sl;
    sm[rr * 384 + 256 + oc] = sr;
  }
  __syncthreads();

  const int y = y2 * 2 + rw;
#pragma unroll
  for (int mt = 0; mt < 4; ++mt)
#pragma unroll
    for (int nt = 0; nt < 2; ++nt) {
      const int px = xh * 64 + px0 + nt * 16 + lm;
#pragma unroll
      for (int r = 0; r < 4; ++r) {
        const int oc = oc0w + mt * 16 + lh * 4 + r;
        float add = sm[rw * 384 + oc];
        if (px == 0)   add -= sm[rw * 384 + 128 + oc];
        if (px == 127) add -= sm[rw * 384 + 256 + oc];
        const float z = acc[mt][nt][r] + add;
        const size_t base = ((size_t)(b * C_ + oc)) * HW_ + (size_t)y * W_ + px;
        const float rx = xin[base];
        out[base] = rx + (z >= 0.f ? z : 0.2f * z);
      }
    }
}

// K4 fallback (R2 version): used when ws_size can't hold T2.
__global__ __launch_bounds__(512, 4) void k_conv_fb(const float* __restrict__ xin,
                                                    const float* __restrict__ to,
                                                    const float* __restrict__ b_f,
                                                    const float* __restrict__ ws,
                                                    float* __restrict__ out) {
  const int bid = blockIdx.x;
  const int nb  = (bid & 7) * 128 + (bid >> 3);
  const int b   = nb >> 7;
  const int y   = nb & 127;
  const int tid = threadIdx.x;

  __shared__ f32x4 ldsbuf[3120];
  char* lp = (char*)ldsbuf;

  f32x4 acc[4][2];
#pragma unroll
  for (int mt = 0; mt < 4; ++mt)
#pragma unroll
    for (int nt = 0; nt < 2; ++nt) acc[mt][nt] = (f32x4)0.f;

  const float* tob = to + (size_t)b * C_ * HW_;
  const unsigned short* wb16 =
      (const unsigned short*)(ws + OFF_WEFF) + (size_t)b * 9 * 128 * 128;

  const int l = tid & 63, wv = tid >> 6;
  const int ocb0 = (wv & 1) * 64, pxb0 = (wv >> 1) * 32;
  const int lm = l & 15, lh = l >> 4;

  for (int cb = 0; cb < 128; cb += 64) {
    __syncthreads();
    {
      const int xg = tid & 31, cq = (tid >> 5) & 15;
      const int cbase = cb + cq * 4;
#pragma unroll
      for (int row = 0; row < 3; ++row) {
        const int y_in = y + row - 1;
        const bool yok = ((unsigned)y_in < 128u);
        const float* src = tob + (size_t)cbase * HW_ + (size_t)y_in * W_;
#pragma unroll
        for (int xb = 0; xb < 5; ++xb) {
          const int xi = xb * 32 + xg;
          if (xi < 130) {
            const int x_in = xi - 1;
            const bool ok = yok && ((unsigned)x_in < 128u);
            float f0 = 0.f, f1 = 0.f, f2 = 0.f, f3 = 0.f;
            if (ok) {
              f0 = src[x_in];
              f1 = src[HW_ + x_in];
              f2 = src[2 * HW_ + x_in];
              f3 = src[3 * HW_ + x_in];
            }
            ushort4 pk;
            pk.x = f2bf(f0); pk.y = f2bf(f1); pk.z = f2bf(f2); pk.w = f2bf(f3);
            const int boff = (row * 130 + xi) * 128 + ((cq * 8) ^ ((xi & 7) << 4));
            *(ushort4*)(lp + boff) = pk;
          }
        }
      }
    }
    __syncthreads();

    for (int tap = 0; tap < 9; ++tap) {
      const int dy = tap / 3, dx = tap - dy * 3;
#pragma unroll
      for (int ks = 0; ks < 2; ++ks) {
        short8 bfr[2];
#pragma unroll
        for (int nt = 0; nt < 2; ++nt) {
          const int xi = pxb0 + nt * 16 + lm + dx;
          const int boff = (dy * 130 + xi) * 128 + ((ks * 64 + lh * 16) ^ ((xi & 7) << 4));
          bfr[nt] = *(const short8*)(lp + boff);
        }
        const int cin = cb + ks * 32 + lh * 8;
#pragma unroll
        for (int mt = 0; mt < 4; ++mt) {
          const int oc = ocb0 + mt * 16 + lm;
          const short8 af = *(const short8*)(wb16 + ((size_t)tap * 128 + oc) * 128 + cin);
          acc[mt][0] = mfma16(af, bfr[0], acc[mt][0]);
          acc[mt][1] = mfma16(af, bfr[1], acc[mt][1]);
        }
      }
    }
  }

  __syncthreads();
  float* sAdd = (float*)ldsbuf;
  float* sLft = sAdd + 128;
  float* sRgt = sAdd + 256;
  if (tid < 128) {
    const float* Tk = ws + OFF_T + (size_t)(b * 128 + tid) * 9;
    float s = Tk[3] + Tk[4] + Tk[5], sl = Tk[3], sr = Tk[5];
    if (y >= 1)   { s += Tk[0] + Tk[1] + Tk[2]; sl += Tk[0]; sr += Tk[2]; }
    if (y <= 126) { s += Tk[6] + Tk[7] + Tk[8]; sl += Tk[6]; sr += Tk[8]; }
    sAdd[tid] = s + b_f[tid]; sLft[tid] = sl; sRgt[tid] = sr;
  }
  __syncthreads();

#pragma unroll
  for (int mt = 0; mt < 4; ++mt)
#pragma unroll
    for (int nt = 0; nt < 2; ++nt) {
      const int px = pxb0 + nt * 16 + lm;
#pragma unroll
      for (int r = 0; r < 4; ++r) {
        const int oc = ocb0 + mt * 16 + lh * 4 + r;
        float add = sAdd[oc];
        if (px == 0)   add -= sLft[oc];
        if (px == 127) add -= sRgt[oc];
        const float z = acc[mt][nt][r] + add;
        const size_t base = ((size_t)(b * C_ + oc)) * HW_ + (size_t)y * W_ + px;
        const float rx = xin[base];
        out[base] = rx + (z >= 0.f ? z : 0.2f * z);
      }
    }
}

extern "C" void kernel_launch(void* const* d_in, const int* in_sizes, int n_in,
                              void* d_out, int out_size, void* d_ws, size_t ws_size,
                              hipStream_t stream) {
  (void)in_sizes; (void)n_in; (void)out_size;
  const float* x    = (const float*)d_in[0];
  const float* to   = (const float*)d_in[1];
  const float* t    = (const float*)d_in[2];
  const float* w_r1 = (const float*)d_in[3];
  const float* b_r1 = (const float*)d_in[4];
  const float* w_r2 = (const float*)d_in[5];
  const float* b_r2 = (const float*)d_in[6];
  const float* w_r3 = (const float*)d_in[7];
  const float* b_r3 = (const float*)d_in[8];
  const float* w_t1 = (const float*)d_in[9];
  const float* b_t1 = (const float*)d_in[10];
  const float* w_t2 = (const float*)d_in[11];
  const float* b_t2 = (const float*)d_in[12];
  const float* w_t3 = (const float*)d_in[13];
  const float* b_t3 = (const float*)d_in[14];
  const float* w_f  = (const float*)d_in[15];
  const float* b_f  = (const float*)d_in[16];
  float* ws  = (float*)d_ws;
  float* out = (float*)d_out;
  unsigned short* t2 = (unsigned short*)(ws + OFF_T2F);
  const bool fast = (ws_size >= WS_NEED);

  k_gram<<<1024, 256, 0, stream>>>(x, to, ws);
  if (fast) k_trz<<<2064, 256, 0, stream>>>(to, t2);
  k_attn<<<8, 256, 0, stream>>>(t, w_r1, b_r1, w_r2, b_r2, w_r3, b_r3,
                                w_t1, b_t1, w_t2, b_t2, w_t3, b_t3, ws);
  k_weff<<<1024, 128, 0, stream>>>(w_f, ws);
  if (fast) k_conv<<<1024, 512, 0, stream>>>(x, b_f, ws, t2, out);
  else      k_conv_fb<<<1024, 512, 0, stream>>>(x, to, b_f, ws, out);
}

// Round 21
// 108.097 us; speedup vs baseline: 1.1144x; 1.0300x over previous
//
#include <hip/hip_runtime.h>
#include <math.h>

#define B_  8
#define C_  128
#define H_  128
#define W_  128
#define HW_ 16384

// ---- workspace layout (float offsets) ----
#define OFF_MPART 0          // [64 bblk][16 ps][256]     = 262144
#define OFF_SPART 262144     // [4 kind][1024 bc][16 ps]  = 65536
#define OFF_WV    348160     // [8][16][16][16]           = 32768
#define OFF_CST   380928     // [8][256]                  = 2048
#define OFF_T     382976     // [8][128][9]               = 9216
#define OFF_WEFF  392192     // bf16 [8][9 tap][128 oc][128 cin] = 1179648 ushort = 589824 fl
#define OFF_T2F   982016     // bf16 T2 [8][130 y'][130 x'][128 c] = 17305600 ushort
#define T2_ROW    16640      // 130*128 shorts
#define T2_BATCH  2163200    // 130*16640 shorts
#define WS_NEED   (982016ull * 4ull + 34611200ull)

typedef __attribute__((ext_vector_type(8))) short short8;
typedef __attribute__((ext_vector_type(4))) float f32x4;

__device__ __forceinline__ unsigned short f2bf(float f) {
  unsigned u = __float_as_uint(f);
  u += 0x7fffu + ((u >> 16) & 1u);
  return (unsigned short)(u >> 16);
}

__device__ __forceinline__ f32x4 mfma16(short8 a, short8 b, f32x4 c) {
  return __builtin_amdgcn_mfma_f32_16x16x32_bf16(a, b, c, 0, 0, 0);
}

// async global->LDS 16B: HW dest = wave-uniform base + lane*16
__device__ __forceinline__ void gl16(const void* g, void* l) {
  const unsigned loff = (unsigned)(unsigned long long)l;
  __builtin_amdgcn_global_load_lds(
      (const __attribute__((address_space(1))) void*)g,
      (__attribute__((address_space(3))) void*)loff, 16, 0, 0);
}

// K_pre (fused k_gram + k_trz): blocks 0..1023 do the MFMA Gram + moments;
// blocks 1024..3087 do the to->T2 transpose (+ border zeroing). The two
// workloads are independent and co-schedule across CUs in ONE dispatch.
__global__ __launch_bounds__(256) void k_pre(const float* __restrict__ x,
                                             const float* __restrict__ to,
                                             float* __restrict__ ws,
                                             unsigned short* __restrict__ t2) {
  const int tid = threadIdx.x;
  __shared__ char shbuf[16384];

  if (blockIdx.x < 1024) {
    // ---- Gram path ----
    const int bid = blockIdx.x;
    const int ps  = bid & 15;
    const int blk = (bid >> 4) & 7;
    const int b   = bid >> 7;
    const int w = tid >> 6, l = tid & 63;
    const int lm = l & 15, lh = l >> 4;
    const int c0 = blk * 16;

    const float* xc = x  + ((size_t)b * C_ + c0 + lm) * HW_;
    const float* tc = to + ((size_t)b * C_ + c0 + lm) * HW_;
    const int p0 = ps * 1024 + w * 256 + lh * 8;

    f32x4 acc = (f32x4)0.f;
    float sx = 0.f, sxx = 0.f, st = 0.f, stt = 0.f;
#pragma unroll
    for (int it = 0; it < 8; ++it) {
      const int p = p0 + it * 32;
      const f32x4 xa = *(const f32x4*)(xc + p);
      const f32x4 xb = *(const f32x4*)(xc + p + 4);
      const f32x4 ta = *(const f32x4*)(tc + p);
      const f32x4 tb = *(const f32x4*)(tc + p + 4);
      short8 xf, tf;
#pragma unroll
      for (int e = 0; e < 4; ++e) {
        xf[e]     = (short)f2bf(xa[e]);
        xf[4 + e] = (short)f2bf(xb[e]);
        tf[e]     = (short)f2bf(ta[e]);
        tf[4 + e] = (short)f2bf(tb[e]);
        sx += xa[e] + xb[e];
        sxx = fmaf(xa[e], xa[e], fmaf(xb[e], xb[e], sxx));
        st += ta[e] + tb[e];
        stt = fmaf(ta[e], ta[e], fmaf(tb[e], tb[e], stt));
      }
      acc = mfma16(xf, tf, acc);   // D[m=x-ch][n=to-ch]
    }

    sx  += __shfl_xor(sx, 16);  sx  += __shfl_xor(sx, 32);
    sxx += __shfl_xor(sxx, 16); sxx += __shfl_xor(sxx, 32);
    st  += __shfl_xor(st, 16);  st  += __shfl_xor(st, 32);
    stt += __shfl_xor(stt, 16); stt += __shfl_xor(stt, 32);

    float* smM = (float*)shbuf;          // [4][256]
    float* smS = smM + 1024;             // [4][4][16]
#pragma unroll
    for (int r = 0; r < 4; ++r)
      smM[w * 256 + (lh * 4 + r) * 16 + lm] = acc[r];   // row=(l>>4)*4+r, col=l&15 (m89)
    if (l < 16) {
      smS[(w * 4 + 0) * 16 + lm] = sx;
      smS[(w * 4 + 1) * 16 + lm] = sxx;
      smS[(w * 4 + 2) * 16 + lm] = st;
      smS[(w * 4 + 3) * 16 + lm] = stt;
    }
    __syncthreads();

    {
      const float s = smM[0 * 256 + tid] + smM[1 * 256 + tid]
                    + smM[2 * 256 + tid] + smM[3 * 256 + tid];
      ws[OFF_MPART + (size_t)((b * 8 + blk) * 16 + ps) * 256 + tid] = s;
    }
    if (tid < 64) {
      const int kind = tid >> 4, ch = tid & 15;
      const float s = smS[(0 * 4 + kind) * 16 + ch] + smS[(1 * 4 + kind) * 16 + ch]
                    + smS[(2 * 4 + kind) * 16 + ch] + smS[(3 * 4 + kind) * 16 + ch];
      ws[OFF_SPART + (size_t)kind * 16384 + (size_t)(b * C_ + c0 + ch) * 16 + ps] = s;
    }
    return;
  }

  // ---- transpose path ----
  const int d = blockIdx.x - 1024;     // 0..2063
  if (d >= 2048) {
    const int e = d - 2048;            // 0..15: b(8) x r(2)
    const int b = e >> 1, r = e & 1;
    unsigned short* row = t2 + (size_t)b * T2_BATCH + (size_t)(r ? 129 : 0) * T2_ROW;
    const short8 z = {0,0,0,0,0,0,0,0};
    for (int idx = tid; idx < 2080; idx += 256)
      *(short8*)(row + (size_t)idx * 8) = z;
    return;
  }
  const int xh = d & 1;
  const int y  = (d >> 1) & 127;
  const int b  = d >> 8;
  char* lds = shbuf;                   // 16 KB

  const int x0 = xh * 64;
  const int xq = tid & 15;             // x-quad
  const int cg = tid >> 4;             // channel group
  const float* srcb = to + ((size_t)b * C_ + cg * 8) * HW_ + (size_t)y * W_ + x0 + xq * 4;
#pragma unroll
  for (int k = 0; k < 8; ++k) {
    const f32x4 v = *(const f32x4*)(srcb + (size_t)k * HW_);
    const int c = cg * 8 + k;
#pragma unroll
    for (int e = 0; e < 4; ++e) {
      const int xl = xq * 4 + e;
      const int boff = xl * 256 + ((2 * c) ^ ((xl & 7) << 4));
      *(unsigned short*)(lds + boff) = f2bf(v[e]);
    }
  }
  __syncthreads();

  unsigned short* rowbase = t2 + (size_t)b * T2_BATCH + (size_t)(y + 1) * T2_ROW;
#pragma unroll
  for (int i = 0; i < 4; ++i) {
    const int xx = tid >> 2;
    const int cs = (tid & 3) + i * 4;   // 0..15
    short8 val = *(short8*)(lds + xx * 256 + ((cs * 16) ^ ((xx & 7) << 4)));
    *(short8*)(rowbase + (size_t)(x0 + xx + 1) * 128 + cs * 8) = val;
  }
  if (tid < 16) {
    short8 z = {0,0,0,0,0,0,0,0};
    if (xh == 0) *(short8*)(rowbase + tid * 8) = z;
    else         *(short8*)(rowbase + (size_t)129 * 128 + tid * 8) = z;
  }
}

// K2 (fused redB+attn): one block per batch.
__global__ __launch_bounds__(256) void k_attn(const float* __restrict__ t,
    const float* __restrict__ w_r1, const float* __restrict__ b_r1,
    const float* __restrict__ w_r2, const float* __restrict__ b_r2,
    const float* __restrict__ w_r3, const float* __restrict__ b_r3,
    const float* __restrict__ w_t1, const float* __restrict__ b_t1,
    const float* __restrict__ w_t2, const float* __restrict__ b_t2,
    const float* __restrict__ w_t3, const float* __restrict__ b_t3,
    float* __restrict__ ws) {
  const int b = blockIdx.x;          // 0..7
  const int tid = threadIdx.x;       // h = tid>>4, i = tid&15
  __shared__ float aQ[256], bQ[256], aK[256], bK[256], aV[256], bV[256];
  __shared__ float rks[256], kAs[256], kBs[256], stos[256];
  __shared__ float Ms[2048];         // [8 blk][256] reduced Gram
  __shared__ float Ss[512];          // [4 kind][128 ch] reduced moments

#pragma unroll
  for (int blk = 0; blk < 8; ++blk) {
    const float* mp = ws + OFF_MPART + (size_t)((b * 8 + blk) * 16) * 256 + tid;
    float s = 0.f;
#pragma unroll
    for (int ps = 0; ps < 16; ++ps) s += mp[ps * 256];
    Ms[blk * 256 + tid] = s;
  }
#pragma unroll
  for (int k2 = 0; k2 < 2; ++k2) {
    const int idx = k2 * 256 + tid;    // 0..511
    const int kind = idx >> 7, ch = idx & 127;
    const float* sp = ws + OFF_SPART + (size_t)kind * 16384
                    + (size_t)(b * C_ + ch) * 16;
    float s = 0.f;
#pragma unroll
    for (int ps = 0; ps < 16; ++ps) s += sp[ps];
    Ss[idx] = s;
  }

  if (tid < 128) {
    const int g = tid;
    float A1[4], B1[4], A2[2], B2[2];
#pragma unroll
    for (int j = 0; j < 4; ++j) { A1[j] = w_r1[g * 4 + j]; B1[j] = b_r1[g * 4 + j]; }
#pragma unroll
    for (int i = 0; i < 2; ++i) {
      A2[i] = 0.f; B2[i] = b_r2[g * 2 + i];
#pragma unroll
      for (int j = 0; j < 4; ++j) {
        const float w = w_r2[(g * 2 + i) * 4 + j];
        A2[i] = fmaf(w, A1[j], A2[i]); B2[i] = fmaf(w, B1[j], B2[i]);
      }
    }
#pragma unroll
    for (int o = 0; o < 2; ++o) {
      float a = 0.f, bb = b_r3[g * 2 + o];
#pragma unroll
      for (int i = 0; i < 2; ++i) {
        const float w = w_r3[(g * 2 + o) * 2 + i];
        a = fmaf(w, A2[i], a); bb = fmaf(w, B2[i], bb);
      }
      aQ[g * 2 + o] = a; bQ[g * 2 + o] = bb;
    }
#pragma unroll
    for (int j = 0; j < 4; ++j) { A1[j] = w_t1[g * 4 + j]; B1[j] = b_t1[g * 4 + j]; }
#pragma unroll
    for (int i = 0; i < 2; ++i) {
      A2[i] = 0.f; B2[i] = b_t2[g * 2 + i];
#pragma unroll
      for (int j = 0; j < 4; ++j) {
        const float w = w_t2[(g * 2 + i) * 4 + j];
        A2[i] = fmaf(w, A1[j], A2[i]); B2[i] = fmaf(w, B1[j], B2[i]);
      }
    }
#pragma unroll
    for (int o = 0; o < 4; ++o) {
      float a = 0.f, bb = b_t3[g * 4 + o];
#pragma unroll
      for (int i = 0; i < 2; ++i) {
        const float w = w_t3[(g * 4 + o) * 2 + i];
        a = fmaf(w, A2[i], a); bb = fmaf(w, B2[i], bb);
      }
      if (o < 2) { aK[g * 2 + o] = a; bK[g * 2 + o] = bb; }
      else       { aV[g * 2 + (o - 2)] = a; bV[g * 2 + (o - 2)] = bb; }
    }
  }
  __syncthreads();

  const float* Sx  = Ss;
  const float* Sxx = Ss + 128;
  const float* Sto = Ss + 256;
  const float* Stt = Ss + 384;

  {
    const int h = tid >> 4, e = h >> 3, blk = h & 7, c0 = blk * 16;
    const int g = c0 + (tid & 15);
    const float a = aK[g * 2 + e], bb = bK[g * 2 + e];
    const float s2 = a * a * Stt[g] + 2.f * a * bb * Sto[g] + bb * bb * 16384.f;
    rks[tid] = 1.f / fmaxf(sqrtf(fmaxf(s2, 0.f)), 1e-12f);
    kAs[tid] = a; kBs[tid] = bb;
    stos[tid] = Sto[g];
  }
  __syncthreads();

  {
    const int h = tid >> 4, i = tid & 15, e = h >> 3, blk = h & 7, c0 = blk * 16;
    const int gi = c0 + i;
    const float gA = aQ[gi * 2 + e], gB = bQ[gi * 2 + e];
    const float sxi = Sx[gi];
    const float q2 = gA * gA * Sxx[gi] + 2.f * gA * gB * sxi + gB * gB * 16384.f;
    const float rnq = 1.f / fmaxf(sqrtf(fmaxf(q2, 0.f)), 1e-12f);
    const float tt = t[h];
    const float* Mrow = Ms + blk * 256 + i * 16;

    float lg[16];
    float mx = -1e30f;
#pragma unroll
    for (int j = 0; j < 16; ++j) {
      const float s = gA * kAs[h * 16 + j] * Mrow[j]
                    + gA * kBs[h * 16 + j] * sxi
                    + gB * kAs[h * 16 + j] * stos[h * 16 + j]
                    + gB * kBs[h * 16 + j] * 16384.f;
      const float l = tt * s * rnq * rks[h * 16 + j];
      lg[j] = l;
      mx = fmaxf(mx, l);
    }
    float den = 0.f;
#pragma unroll
    for (int j = 0; j < 16; ++j) { const float ev = expf(lg[j] - mx); lg[j] = ev; den += ev; }
    const float inv = 1.f / den;
    float cs = 0.f;
    float* WVp = ws + OFF_WV + (size_t)(b * 16 + h) * 256 + i * 16;
#pragma unroll
    for (int j = 0; j < 16; ++j) {
      const float aa = lg[j] * inv;
      const int gj = c0 + j;
      WVp[j] = aa * aV[gj * 2 + e];
      cs = fmaf(aa, bV[gj * 2 + e], cs);
    }
    ws[OFF_CST + b * 256 + i * 16 + h] = cs;
  }
}

// K3: fold attention into per-batch bf16 conv weights + constant taps.
__global__ __launch_bounds__(128) void k_weff(const float* __restrict__ w_f,
                                              float* __restrict__ ws) {
  const int b = blockIdx.x >> 7, oc = blockIdx.x & 127;
  const int c = threadIdx.x, blk = c >> 4, j = c & 15;
  const float* WVb = ws + OFF_WV;
  float acc[9];
#pragma unroll
  for (int k = 0; k < 9; ++k) acc[k] = 0.f;
#pragma unroll
  for (int e = 0; e < 2; ++e) {
    const int h = e * 8 + blk;
#pragma unroll
    for (int i = 0; i < 16; ++i) {
      const float coef = WVb[((size_t)(b * 16 + h) * 16 + i) * 16 + j];
      const float* wf = w_f + (size_t)(oc * 256 + i * 16 + h) * 9;
#pragma unroll
      for (int k = 0; k < 9; ++k) acc[k] = fmaf(wf[k], coef, acc[k]);
    }
  }
  unsigned short* wb16 = (unsigned short*)(ws + OFF_WEFF);
#pragma unroll
  for (int k = 0; k < 9; ++k)
    wb16[(((size_t)(b * 9 + k)) * 128 + oc) * 128 + c] = f2bf(acc[k]);

  __shared__ float tp[9][128];
  float tl[9];
#pragma unroll
  for (int k = 0; k < 9; ++k) tl[k] = 0.f;
  const float* cst = ws + OFF_CST + b * 256;
  for (int cc = c; cc < 256; cc += 128) {
    const float cv = cst[cc];
    const float* wf = w_f + (size_t)(oc * 256 + cc) * 9;
#pragma unroll
    for (int k = 0; k < 9; ++k) tl[k] = fmaf(wf[k], cv, tl[k]);
  }
#pragma unroll
  for (int k = 0; k < 9; ++k) tp[k][c] = tl[k];
  __syncthreads();
  for (int s = 64; s > 0; s >>= 1) {
    if (c < s) {
#pragma unroll
      for (int k = 0; k < 9; ++k) tp[k][c] += tp[k][c + s];
    }
    __syncthreads();
  }
  if (c < 9) ws[OFF_T + ((size_t)b * 128 + oc) * 9 + c] = tp[c][0];
}

// K4 (R10/R15 best-measured version): m97-style double-buffered gload_lds
// conv-GEMM. Block = (b, y): 128 oc x 128 px, 18 steps (9 taps x 2 cin-halves).
// LDS: A[2][128][64] + B[2][128][64] bf16 = 64 KiB -> 2 blocks/CU.
__global__ __launch_bounds__(512, 4) void k_conv(const float* __restrict__ xin,
                                                 const float* __restrict__ b_f,
                                                 const float* __restrict__ ws,
                                                 const unsigned short* __restrict__ t2,
                                                 float* __restrict__ out) {
  const int d = blockIdx.x;           // 1024 = b(8, fast -> XCD) * y(128)
  const int b = d & 7;
  const int y = d >> 3;
  const int tid = threadIdx.x;

  __shared__ unsigned short As[2][128 * 64];
  __shared__ unsigned short Bs[2][128 * 64];

  const unsigned short* wb = (const unsigned short*)(ws + OFF_WEFF)
      + (size_t)b * 9 * 16384;
  const unsigned short* t2y = t2 + (size_t)b * T2_BATCH + (size_t)y * T2_ROW;

  const int l = tid & 63;
  const int lm = l & 15, lh = l >> 4;
  const int wv = tid >> 6;
  const int oc0w = (wv >> 1) * 32;    // 4 wave-rows of 32 oc
  const int px0w = (wv & 1) * 64;     // 2 wave-cols of 64 px

  const int trow0 = tid >> 3, tci0 = tid & 7;
  const unsigned udst0 = (unsigned)((tid & ~63) * 16);
  const unsigned udst1 = udst0 + 512u * 16u;

#define STAGE(BUF, S)                                                          \
  {                                                                            \
    const int tap_ = (S) >> 1, ks_ = (S) & 1;                                  \
    const int dy_ = tap_ / 3, dx_ = tap_ - dy_ * 3;                            \
    const unsigned short* asrc = wb + (size_t)tap_ * 16384 + ks_ * 64;         \
    const unsigned short* bsrc = t2y + (size_t)dy_ * T2_ROW + dx_ * 128 + ks_ * 64; \
    gl16(asrc + (size_t)trow0 * 128 + ((tci0 ^ (trow0 & 7)) << 3),             \
         (char*)&As[BUF][0] + udst0);                                          \
    gl16(asrc + (size_t)(trow0 + 64) * 128 + ((tci0 ^ ((trow0 + 64) & 7)) << 3), \
         (char*)&As[BUF][0] + udst1);                                          \
    gl16(bsrc + (size_t)trow0 * 128 + ((tci0 ^ (trow0 & 7)) << 3),             \
         (char*)&Bs[BUF][0] + udst0);                                          \
    gl16(bsrc + (size_t)(trow0 + 64) * 128 + ((tci0 ^ ((trow0 + 64) & 7)) << 3), \
         (char*)&Bs[BUF][0] + udst1);                                          \
  }

  f32x4 acc[2][4];
#pragma unroll
  for (int mt = 0; mt < 2; ++mt)
#pragma unroll
    for (int nt = 0; nt < 4; ++nt) acc[mt][nt] = (f32x4)0.f;

  STAGE(0, 0);
  __syncthreads();   // drains vmcnt -> buf0 ready

  int cur = 0;
#pragma unroll 1
  for (int s = 0; s < 18; ++s) {
    if (s + 1 < 18) STAGE(cur ^ 1, s + 1);   // async prefetch under MFMAs

    const char* Ab = (const char*)&As[cur][0];
    const char* Bb = (const char*)&Bs[cur][0];
#pragma unroll
    for (int ki = 0; ki < 2; ++ki) {
      short8 af[2], bfr[4];
#pragma unroll
      for (int mt = 0; mt < 2; ++mt) {
        const int oc = oc0w + mt * 16 + lm;
        af[mt] = *(const short8*)(Ab + oc * 128 + (((ki * 4 + lh) ^ (oc & 7)) << 4));
      }
#pragma unroll
      for (int nt = 0; nt < 4; ++nt) {
        const int px = px0w + nt * 16 + lm;
        bfr[nt] = *(const short8*)(Bb + px * 128 + (((ki * 4 + lh) ^ (px & 7)) << 4));
      }
#pragma unroll
      for (int mt = 0; mt < 2; ++mt) {
        acc[mt][0] = mfma16(af[mt], bfr[0], acc[mt][0]);
        acc[mt][1] = mfma16(af[mt], bfr[1], acc[mt][1]);
        acc[mt][2] = mfma16(af[mt], bfr[2], acc[mt][2]);
        acc[mt][3] = mfma16(af[mt], bfr[3], acc[mt][3]);
      }
    }
    __syncthreads();   // waits prefetch (vmcnt) + protects buf overwrite
    cur ^= 1;
  }
#undef STAGE

  // epilogue: per-oc constant terms (reuse As as f32 scratch)
  float* sm = (float*)&As[0][0];   // [3][128]: add, left, right
  if (tid < 128) {
    const float* Tk = ws + OFF_T + (size_t)(b * 128 + tid) * 9;
    float s = Tk[3] + Tk[4] + Tk[5], sl = Tk[3], sr = Tk[5];
    if (y >= 1)   { s += Tk[0] + Tk[1] + Tk[2]; sl += Tk[0]; sr += Tk[2]; }
    if (y <= 126) { s += Tk[6] + Tk[7] + Tk[8]; sl += Tk[6]; sr += Tk[8]; }
    sm[tid] = s + b_f[tid]; sm[128 + tid] = sl; sm[256 + tid] = sr;
  }
  __syncthreads();

#pragma unroll
  for (int mt = 0; mt < 2; ++mt)
#pragma unroll
    for (int nt = 0; nt < 4; ++nt) {
      const int px = px0w + nt * 16 + lm;
#pragma unroll
      for (int r = 0; r < 4; ++r) {
        const int oc = oc0w + mt * 16 + lh * 4 + r;
        float add = sm[oc];
        if (px == 0)   add -= sm[128 + oc];
        if (px == 127) add -= sm[256 + oc];
        const float z = acc[mt][nt][r] + add;
        const size_t base = ((size_t)(b * C_ + oc)) * HW_ + (size_t)y * W_ + px;
        const float rx = xin[base];
        out[base] = rx + (z >= 0.f ? z : 0.2f * z);
      }
    }
}

// K4 fallback (R2 version): used when ws_size can't hold T2.
__global__ __launch_bounds__(512, 4) void k_conv_fb(const float* __restrict__ xin,
                                                    const float* __restrict__ to,
                                                    const float* __restrict__ b_f,
                                                    const float* __restrict__ ws,
                                                    float* __restrict__ out) {
  const int bid = blockIdx.x;
  const int nb  = (bid & 7) * 128 + (bid >> 3);
  const int b   = nb >> 7;
  const int y   = nb & 127;
  const int tid = threadIdx.x;

  __shared__ f32x4 ldsbuf[3120];
  char* lp = (char*)ldsbuf;

  f32x4 acc[4][2];
#pragma unroll
  for (int mt = 0; mt < 4; ++mt)
#pragma unroll
    for (int nt = 0; nt < 2; ++nt) acc[mt][nt] = (f32x4)0.f;

  const float* tob = to + (size_t)b * C_ * HW_;
  const unsigned short* wb16 =
      (const unsigned short*)(ws + OFF_WEFF) + (size_t)b * 9 * 128 * 128;

  const int l = tid & 63, wv = tid >> 6;
  const int ocb0 = (wv & 1) * 64, pxb0 = (wv >> 1) * 32;
  const int lm = l & 15, lh = l >> 4;

  for (int cb = 0; cb < 128; cb += 64) {
    __syncthreads();
    {
      const int xg = tid & 31, cq = (tid >> 5) & 15;
      const int cbase = cb + cq * 4;
#pragma unroll
      for (int row = 0; row < 3; ++row) {
        const int y_in = y + row - 1;
        const bool yok = ((unsigned)y_in < 128u);
        const float* src = tob + (size_t)cbase * HW_ + (size_t)y_in * W_;
#pragma unroll
        for (int xb = 0; xb < 5; ++xb) {
          const int xi = xb * 32 + xg;
          if (xi < 130) {
            const int x_in = xi - 1;
            const bool ok = yok && ((unsigned)x_in < 128u);
            float f0 = 0.f, f1 = 0.f, f2 = 0.f, f3 = 0.f;
            if (ok) {
              f0 = src[x_in];
              f1 = src[HW_ + x_in];
              f2 = src[2 * HW_ + x_in];
              f3 = src[3 * HW_ + x_in];
            }
            ushort4 pk;
            pk.x = f2bf(f0); pk.y = f2bf(f1); pk.z = f2bf(f2); pk.w = f2bf(f3);
            const int boff = (row * 130 + xi) * 128 + ((cq * 8) ^ ((xi & 7) << 4));
            *(ushort4*)(lp + boff) = pk;
          }
        }
      }
    }
    __syncthreads();

    for (int tap = 0; tap < 9; ++tap) {
      const int dy = tap / 3, dx = tap - dy * 3;
#pragma unroll
      for (int ks = 0; ks < 2; ++ks) {
        short8 bfr[2];
#pragma unroll
        for (int nt = 0; nt < 2; ++nt) {
          const int xi = pxb0 + nt * 16 + lm + dx;
          const int boff = (dy * 130 + xi) * 128 + ((ks * 64 + lh * 16) ^ ((xi & 7) << 4));
          bfr[nt] = *(const short8*)(lp + boff);
        }
        const int cin = cb + ks * 32 + lh * 8;
#pragma unroll
        for (int mt = 0; mt < 4; ++mt) {
          const int oc = ocb0 + mt * 16 + lm;
          const short8 af = *(const short8*)(wb16 + ((size_t)tap * 128 + oc) * 128 + cin);
          acc[mt][0] = mfma16(af, bfr[0], acc[mt][0]);
          acc[mt][1] = mfma16(af, bfr[1], acc[mt][1]);
        }
      }
    }
  }

  __syncthreads();
  float* sAdd = (float*)ldsbuf;
  float* sLft = sAdd + 128;
  float* sRgt = sAdd + 256;
  if (tid < 128) {
    const float* Tk = ws + OFF_T + (size_t)(b * 128 + tid) * 9;
    float s = Tk[3] + Tk[4] + Tk[5], sl = Tk[3], sr = Tk[5];
    if (y >= 1)   { s += Tk[0] + Tk[1] + Tk[2]; sl += Tk[0]; sr += Tk[2]; }
    if (y <= 126) { s += Tk[6] + Tk[7] + Tk[8]; sl += Tk[6]; sr += Tk[8]; }
    sAdd[tid] = s + b_f[tid]; sLft[tid] = sl; sRgt[tid] = sr;
  }
  __syncthreads();

#pragma unroll
  for (int mt = 0; mt < 4; ++mt)
#pragma unroll
    for (int nt = 0; nt < 2; ++nt) {
      const int px = pxb0 + nt * 16 + lm;
#pragma unroll
      for (int r = 0; r < 4; ++r) {
        const int oc = ocb0 + mt * 16 + lh * 4 + r;
        float add = sAdd[oc];
        if (px == 0)   add -= sLft[oc];
        if (px == 127) add -= sRgt[oc];
        const float z = acc[mt][nt][r] + add;
        const size_t base = ((size_t)(b * C_ + oc)) * HW_ + (size_t)y * W_ + px;
        const float rx = xin[base];
        out[base] = rx + (z >= 0.f ? z : 0.2f * z);
      }
    }
}

extern "C" void kernel_launch(void* const* d_in, const int* in_sizes, int n_in,
                              void* d_out, int out_size, void* d_ws, size_t ws_size,
                              hipStream_t stream) {
  (void)in_sizes; (void)n_in; (void)out_size;
  const float* x    = (const float*)d_in[0];
  const float* to   = (const float*)d_in[1];
  const float* t    = (const float*)d_in[2];
  const float* w_r1 = (const float*)d_in[3];
  const float* b_r1 = (const float*)d_in[4];
  const float* w_r2 = (const float*)d_in[5];
  const float* b_r2 = (const float*)d_in[6];
  const float* w_r3 = (const float*)d_in[7];
  const float* b_r3 = (const float*)d_in[8];
  const float* w_t1 = (const float*)d_in[9];
  const float* b_t1 = (const float*)d_in[10];
  const float* w_t2 = (const float*)d_in[11];
  const float* b_t2 = (const float*)d_in[12];
  const float* w_t3 = (const float*)d_in[13];
  const float* b_t3 = (const float*)d_in[14];
  const float* w_f  = (const float*)d_in[15];
  const float* b_f  = (const float*)d_in[16];
  float* ws  = (float*)d_ws;
  float* out = (float*)d_out;
  unsigned short* t2 = (unsigned short*)(ws + OFF_T2F);
  const bool fast = (ws_size >= WS_NEED);

  if (fast) {
    k_pre<<<3088, 256, 0, stream>>>(x, to, ws, t2);
  } else {
    k_pre<<<1024, 256, 0, stream>>>(x, to, ws, t2);  // gram blocks only
  }
  k_attn<<<8, 256, 0, stream>>>(t, w_r1, b_r1, w_r2, b_r2, w_r3, b_r3,
                                w_t1, b_t1, w_t2, b_t2, w_t3, b_t3, ws);
  k_weff<<<1024, 128, 0, stream>>>(w_f, ws);
  if (fast) k_conv<<<1024, 512, 0, stream>>>(x, b_f, ws, t2, out);
  else      k_conv_fb<<<1024, 512, 0, stream>>>(x, to, b_f, ws, out);
}

// Round 22
// 105.414 us; speedup vs baseline: 1.1428x; 1.0255x over previous
//
#include <hip/hip_runtime.h>
#include <math.h>

#define B_  8
#define C_  128
#define H_  128
#define W_  128
#define HW_ 16384

// ---- workspace layout (float offsets) ----
#define OFF_MPART 0          // [64 bblk][16 ps][256]     = 262144
#define OFF_SPART 262144     // [4 kind][1024 bc][16 ps]  = 65536
#define OFF_WV    348160     // [8][16][16][16]           = 32768
#define OFF_CST   380928     // [8][256]                  = 2048
#define OFF_T     382976     // [8][128][9]               = 9216
#define OFF_WEFF  392192     // bf16 [8][9 tap][128 oc][128 cin] = 1179648 ushort = 589824 fl
#define OFF_T2F   982016     // bf16 T2 [8][130 y'][130 x'][128 c] = 17305600 ushort
#define T2_ROW    16640      // 130*128 shorts
#define T2_BATCH  2163200    // 130*16640 shorts
#define WS_NEED   (982016ull * 4ull + 34611200ull)

typedef __attribute__((ext_vector_type(8))) short short8;
typedef __attribute__((ext_vector_type(4))) float f32x4;

__device__ __forceinline__ unsigned short f2bf(float f) {
  unsigned u = __float_as_uint(f);
  u += 0x7fffu + ((u >> 16) & 1u);
  return (unsigned short)(u >> 16);
}

__device__ __forceinline__ f32x4 mfma16(short8 a, short8 b, f32x4 c) {
  return __builtin_amdgcn_mfma_f32_16x16x32_bf16(a, b, c, 0, 0, 0);
}

// async global->LDS 16B: HW dest = wave-uniform base + lane*16
__device__ __forceinline__ void gl16(const void* g, void* l) {
  const unsigned loff = (unsigned)(unsigned long long)l;
  __builtin_amdgcn_global_load_lds(
      (const __attribute__((address_space(1))) void*)g,
      (__attribute__((address_space(3))) void*)loff, 16, 0, 0);
}

// K_pre (fused k_gram + k_trz): blocks 0..1023 do the MFMA Gram + moments;
// blocks 1024..3087 do the to->T2 transpose (+ border zeroing).
__global__ __launch_bounds__(256) void k_pre(const float* __restrict__ x,
                                             const float* __restrict__ to,
                                             float* __restrict__ ws,
                                             unsigned short* __restrict__ t2) {
  const int tid = threadIdx.x;
  __shared__ char shbuf[16384];

  if (blockIdx.x < 1024) {
    // ---- Gram path ----
    const int bid = blockIdx.x;
    const int ps  = bid & 15;
    const int blk = (bid >> 4) & 7;
    const int b   = bid >> 7;
    const int w = tid >> 6, l = tid & 63;
    const int lm = l & 15, lh = l >> 4;
    const int c0 = blk * 16;

    const float* xc = x  + ((size_t)b * C_ + c0 + lm) * HW_;
    const float* tc = to + ((size_t)b * C_ + c0 + lm) * HW_;
    const int p0 = ps * 1024 + w * 256 + lh * 8;

    f32x4 acc = (f32x4)0.f;
    float sx = 0.f, sxx = 0.f, st = 0.f, stt = 0.f;
#pragma unroll
    for (int it = 0; it < 8; ++it) {
      const int p = p0 + it * 32;
      const f32x4 xa = *(const f32x4*)(xc + p);
      const f32x4 xb = *(const f32x4*)(xc + p + 4);
      const f32x4 ta = *(const f32x4*)(tc + p);
      const f32x4 tb = *(const f32x4*)(tc + p + 4);
      short8 xf, tf;
#pragma unroll
      for (int e = 0; e < 4; ++e) {
        xf[e]     = (short)f2bf(xa[e]);
        xf[4 + e] = (short)f2bf(xb[e]);
        tf[e]     = (short)f2bf(ta[e]);
        tf[4 + e] = (short)f2bf(tb[e]);
        sx += xa[e] + xb[e];
        sxx = fmaf(xa[e], xa[e], fmaf(xb[e], xb[e], sxx));
        st += ta[e] + tb[e];
        stt = fmaf(ta[e], ta[e], fmaf(tb[e], tb[e], stt));
      }
      acc = mfma16(xf, tf, acc);   // D[m=x-ch][n=to-ch]
    }

    sx  += __shfl_xor(sx, 16);  sx  += __shfl_xor(sx, 32);
    sxx += __shfl_xor(sxx, 16); sxx += __shfl_xor(sxx, 32);
    st  += __shfl_xor(st, 16);  st  += __shfl_xor(st, 32);
    stt += __shfl_xor(stt, 16); stt += __shfl_xor(stt, 32);

    float* smM = (float*)shbuf;          // [4][256]
    float* smS = smM + 1024;             // [4][4][16]
#pragma unroll
    for (int r = 0; r < 4; ++r)
      smM[w * 256 + (lh * 4 + r) * 16 + lm] = acc[r];   // row=(l>>4)*4+r, col=l&15 (m89)
    if (l < 16) {
      smS[(w * 4 + 0) * 16 + lm] = sx;
      smS[(w * 4 + 1) * 16 + lm] = sxx;
      smS[(w * 4 + 2) * 16 + lm] = st;
      smS[(w * 4 + 3) * 16 + lm] = stt;
    }
    __syncthreads();

    {
      const float s = smM[0 * 256 + tid] + smM[1 * 256 + tid]
                    + smM[2 * 256 + tid] + smM[3 * 256 + tid];
      ws[OFF_MPART + (size_t)((b * 8 + blk) * 16 + ps) * 256 + tid] = s;
    }
    if (tid < 64) {
      const int kind = tid >> 4, ch = tid & 15;
      const float s = smS[(0 * 4 + kind) * 16 + ch] + smS[(1 * 4 + kind) * 16 + ch]
                    + smS[(2 * 4 + kind) * 16 + ch] + smS[(3 * 4 + kind) * 16 + ch];
      ws[OFF_SPART + (size_t)kind * 16384 + (size_t)(b * C_ + c0 + ch) * 16 + ps] = s;
    }
    return;
  }

  // ---- transpose path ----
  const int d = blockIdx.x - 1024;     // 0..2063
  if (d >= 2048) {
    const int e = d - 2048;            // 0..15: b(8) x r(2)
    const int b = e >> 1, r = e & 1;
    unsigned short* row = t2 + (size_t)b * T2_BATCH + (size_t)(r ? 129 : 0) * T2_ROW;
    const short8 z = {0,0,0,0,0,0,0,0};
    for (int idx = tid; idx < 2080; idx += 256)
      *(short8*)(row + (size_t)idx * 8) = z;
    return;
  }
  const int xh = d & 1;
  const int y  = (d >> 1) & 127;
  const int b  = d >> 8;
  char* lds = shbuf;                   // 16 KB

  const int x0 = xh * 64;
  const int xq = tid & 15;             // x-quad
  const int cg = tid >> 4;             // channel group
  const float* srcb = to + ((size_t)b * C_ + cg * 8) * HW_ + (size_t)y * W_ + x0 + xq * 4;
#pragma unroll
  for (int k = 0; k < 8; ++k) {
    const f32x4 v = *(const f32x4*)(srcb + (size_t)k * HW_);
    const int c = cg * 8 + k;
#pragma unroll
    for (int e = 0; e < 4; ++e) {
      const int xl = xq * 4 + e;
      const int boff = xl * 256 + ((2 * c) ^ ((xl & 7) << 4));
      *(unsigned short*)(lds + boff) = f2bf(v[e]);
    }
  }
  __syncthreads();

  unsigned short* rowbase = t2 + (size_t)b * T2_BATCH + (size_t)(y + 1) * T2_ROW;
#pragma unroll
  for (int i = 0; i < 4; ++i) {
    const int xx = tid >> 2;
    const int cs = (tid & 3) + i * 4;   // 0..15
    short8 val = *(short8*)(lds + xx * 256 + ((cs * 16) ^ ((xx & 7) << 4)));
    *(short8*)(rowbase + (size_t)(x0 + xx + 1) * 128 + cs * 8) = val;
  }
  if (tid < 16) {
    short8 z = {0,0,0,0,0,0,0,0};
    if (xh == 0) *(short8*)(rowbase + tid * 8) = z;
    else         *(short8*)(rowbase + (size_t)129 * 128 + tid * 8) = z;
  }
}

// K2 (fused redB+attn): one block per batch.
__global__ __launch_bounds__(256) void k_attn(const float* __restrict__ t,
    const float* __restrict__ w_r1, const float* __restrict__ b_r1,
    const float* __restrict__ w_r2, const float* __restrict__ b_r2,
    const float* __restrict__ w_r3, const float* __restrict__ b_r3,
    const float* __restrict__ w_t1, const float* __restrict__ b_t1,
    const float* __restrict__ w_t2, const float* __restrict__ b_t2,
    const float* __restrict__ w_t3, const float* __restrict__ b_t3,
    float* __restrict__ ws) {
  const int b = blockIdx.x;          // 0..7
  const int tid = threadIdx.x;       // h = tid>>4, i = tid&15
  __shared__ float aQ[256], bQ[256], aK[256], bK[256], aV[256], bV[256];
  __shared__ float rks[256], kAs[256], kBs[256], stos[256];
  __shared__ float Ms[2048];         // [8 blk][256] reduced Gram
  __shared__ float Ss[512];          // [4 kind][128 ch] reduced moments

#pragma unroll
  for (int blk = 0; blk < 8; ++blk) {
    const float* mp = ws + OFF_MPART + (size_t)((b * 8 + blk) * 16) * 256 + tid;
    float s = 0.f;
#pragma unroll
    for (int ps = 0; ps < 16; ++ps) s += mp[ps * 256];
    Ms[blk * 256 + tid] = s;
  }
#pragma unroll
  for (int k2 = 0; k2 < 2; ++k2) {
    const int idx = k2 * 256 + tid;    // 0..511
    const int kind = idx >> 7, ch = idx & 127;
    const float* sp = ws + OFF_SPART + (size_t)kind * 16384
                    + (size_t)(b * C_ + ch) * 16;
    float s = 0.f;
#pragma unroll
    for (int ps = 0; ps < 16; ++ps) s += sp[ps];
    Ss[idx] = s;
  }

  if (tid < 128) {
    const int g = tid;
    float A1[4], B1[4], A2[2], B2[2];
#pragma unroll
    for (int j = 0; j < 4; ++j) { A1[j] = w_r1[g * 4 + j]; B1[j] = b_r1[g * 4 + j]; }
#pragma unroll
    for (int i = 0; i < 2; ++i) {
      A2[i] = 0.f; B2[i] = b_r2[g * 2 + i];
#pragma unroll
      for (int j = 0; j < 4; ++j) {
        const float w = w_r2[(g * 2 + i) * 4 + j];
        A2[i] = fmaf(w, A1[j], A2[i]); B2[i] = fmaf(w, B1[j], B2[i]);
      }
    }
#pragma unroll
    for (int o = 0; o < 2; ++o) {
      float a = 0.f, bb = b_r3[g * 2 + o];
#pragma unroll
      for (int i = 0; i < 2; ++i) {
        const float w = w_r3[(g * 2 + o) * 2 + i];
        a = fmaf(w, A2[i], a); bb = fmaf(w, B2[i], bb);
      }
      aQ[g * 2 + o] = a; bQ[g * 2 + o] = bb;
    }
#pragma unroll
    for (int j = 0; j < 4; ++j) { A1[j] = w_t1[g * 4 + j]; B1[j] = b_t1[g * 4 + j]; }
#pragma unroll
    for (int i = 0; i < 2; ++i) {
      A2[i] = 0.f; B2[i] = b_t2[g * 2 + i];
#pragma unroll
      for (int j = 0; j < 4; ++j) {
        const float w = w_t2[(g * 2 + i) * 4 + j];
        A2[i] = fmaf(w, A1[j], A2[i]); B2[i] = fmaf(w, B1[j], B2[i]);
      }
    }
#pragma unroll
    for (int o = 0; o < 4; ++o) {
      float a = 0.f, bb = b_t3[g * 4 + o];
#pragma unroll
      for (int i = 0; i < 2; ++i) {
        const float w = w_t3[(g * 4 + o) * 2 + i];
        a = fmaf(w, A2[i], a); bb = fmaf(w, B2[i], bb);
      }
      if (o < 2) { aK[g * 2 + o] = a; bK[g * 2 + o] = bb; }
      else       { aV[g * 2 + (o - 2)] = a; bV[g * 2 + (o - 2)] = bb; }
    }
  }
  __syncthreads();

  const float* Sx  = Ss;
  const float* Sxx = Ss + 128;
  const float* Sto = Ss + 256;
  const float* Stt = Ss + 384;

  {
    const int h = tid >> 4, e = h >> 3, blk = h & 7, c0 = blk * 16;
    const int g = c0 + (tid & 15);
    const float a = aK[g * 2 + e], bb = bK[g * 2 + e];
    const float s2 = a * a * Stt[g] + 2.f * a * bb * Sto[g] + bb * bb * 16384.f;
    rks[tid] = 1.f / fmaxf(sqrtf(fmaxf(s2, 0.f)), 1e-12f);
    kAs[tid] = a; kBs[tid] = bb;
    stos[tid] = Sto[g];
  }
  __syncthreads();

  {
    const int h = tid >> 4, i = tid & 15, e = h >> 3, blk = h & 7, c0 = blk * 16;
    const int gi = c0 + i;
    const float gA = aQ[gi * 2 + e], gB = bQ[gi * 2 + e];
    const float sxi = Sx[gi];
    const float q2 = gA * gA * Sxx[gi] + 2.f * gA * gB * sxi + gB * gB * 16384.f;
    const float rnq = 1.f / fmaxf(sqrtf(fmaxf(q2, 0.f)), 1e-12f);
    const float tt = t[h];
    const float* Mrow = Ms + blk * 256 + i * 16;

    float lg[16];
    float mx = -1e30f;
#pragma unroll
    for (int j = 0; j < 16; ++j) {
      const float s = gA * kAs[h * 16 + j] * Mrow[j]
                    + gA * kBs[h * 16 + j] * sxi
                    + gB * kAs[h * 16 + j] * stos[h * 16 + j]
                    + gB * kBs[h * 16 + j] * 16384.f;
      const float l = tt * s * rnq * rks[h * 16 + j];
      lg[j] = l;
      mx = fmaxf(mx, l);
    }
    float den = 0.f;
#pragma unroll
    for (int j = 0; j < 16; ++j) { const float ev = expf(lg[j] - mx); lg[j] = ev; den += ev; }
    const float inv = 1.f / den;
    float cs = 0.f;
    float* WVp = ws + OFF_WV + (size_t)(b * 16 + h) * 256 + i * 16;
#pragma unroll
    for (int j = 0; j < 16; ++j) {
      const float aa = lg[j] * inv;
      const int gj = c0 + j;
      WVp[j] = aa * aV[gj * 2 + e];
      cs = fmaf(aa, bV[gj * 2 + e], cs);
    }
    ws[OFF_CST + b * 256 + i * 16 + h] = cs;
  }
}

// K3: fold attention into per-batch bf16 conv weights + constant taps.
__global__ __launch_bounds__(128) void k_weff(const float* __restrict__ w_f,
                                              float* __restrict__ ws) {
  const int b = blockIdx.x >> 7, oc = blockIdx.x & 127;
  const int c = threadIdx.x, blk = c >> 4, j = c & 15;
  const float* WVb = ws + OFF_WV;
  float acc[9];
#pragma unroll
  for (int k = 0; k < 9; ++k) acc[k] = 0.f;
#pragma unroll
  for (int e = 0; e < 2; ++e) {
    const int h = e * 8 + blk;
#pragma unroll
    for (int i = 0; i < 16; ++i) {
      const float coef = WVb[((size_t)(b * 16 + h) * 16 + i) * 16 + j];
      const float* wf = w_f + (size_t)(oc * 256 + i * 16 + h) * 9;
#pragma unroll
      for (int k = 0; k < 9; ++k) acc[k] = fmaf(wf[k], coef, acc[k]);
    }
  }
  unsigned short* wb16 = (unsigned short*)(ws + OFF_WEFF);
#pragma unroll
  for (int k = 0; k < 9; ++k)
    wb16[(((size_t)(b * 9 + k)) * 128 + oc) * 128 + c] = f2bf(acc[k]);

  __shared__ float tp[9][128];
  float tl[9];
#pragma unroll
  for (int k = 0; k < 9; ++k) tl[k] = 0.f;
  const float* cst = ws + OFF_CST + b * 256;
  for (int cc = c; cc < 256; cc += 128) {
    const float cv = cst[cc];
    const float* wf = w_f + (size_t)(oc * 256 + cc) * 9;
#pragma unroll
    for (int k = 0; k < 9; ++k) tl[k] = fmaf(wf[k], cv, tl[k]);
  }
#pragma unroll
  for (int k = 0; k < 9; ++k) tp[k][c] = tl[k];
  __syncthreads();
  for (int s = 64; s > 0; s >>= 1) {
    if (c < s) {
#pragma unroll
      for (int k = 0; k < 9; ++k) tp[k][c] += tp[k][c + s];
    }
    __syncthreads();
  }
  if (c < 9) ws[OFF_T + ((size_t)b * 128 + oc) * 9 + c] = tp[c][0];
}

// K4: R21 structure + ISSUE-EARLY residual x loads (T14): the 16 epilogue
// xin loads are issued before the K-loop; their L2/L3 latency hides under the
// 18-step pipeline instead of serializing at block end.
__global__ __launch_bounds__(512, 4) void k_conv(const float* __restrict__ xin,
                                                 const float* __restrict__ b_f,
                                                 const float* __restrict__ ws,
                                                 const unsigned short* __restrict__ t2,
                                                 float* __restrict__ out) {
  const int d = blockIdx.x;           // 1024 = b(8, fast -> XCD) * y(128)
  const int b = d & 7;
  const int y = d >> 3;
  const int tid = threadIdx.x;

  __shared__ unsigned short As[2][128 * 64];
  __shared__ unsigned short Bs[2][128 * 64];

  const unsigned short* wb = (const unsigned short*)(ws + OFF_WEFF)
      + (size_t)b * 9 * 16384;
  const unsigned short* t2y = t2 + (size_t)b * T2_BATCH + (size_t)y * T2_ROW;

  const int l = tid & 63;
  const int lm = l & 15, lh = l >> 4;
  const int wv = tid >> 6;
  const int oc0w = (wv >> 1) * 32;    // 4 wave-rows of 32 oc
  const int px0w = (wv & 1) * 64;     // 2 wave-cols of 64 px

  const int trow0 = tid >> 3, tci0 = tid & 7;
  const unsigned udst0 = (unsigned)((tid & ~63) * 16);
  const unsigned udst1 = udst0 + 512u * 16u;

#define STAGE(BUF, S)                                                          \
  {                                                                            \
    const int tap_ = (S) >> 1, ks_ = (S) & 1;                                  \
    const int dy_ = tap_ / 3, dx_ = tap_ - dy_ * 3;                            \
    const unsigned short* asrc = wb + (size_t)tap_ * 16384 + ks_ * 64;         \
    const unsigned short* bsrc = t2y + (size_t)dy_ * T2_ROW + dx_ * 128 + ks_ * 64; \
    gl16(asrc + (size_t)trow0 * 128 + ((tci0 ^ (trow0 & 7)) << 3),             \
         (char*)&As[BUF][0] + udst0);                                          \
    gl16(asrc + (size_t)(trow0 + 64) * 128 + ((tci0 ^ ((trow0 + 64) & 7)) << 3), \
         (char*)&As[BUF][0] + udst1);                                          \
    gl16(bsrc + (size_t)trow0 * 128 + ((tci0 ^ (trow0 & 7)) << 3),             \
         (char*)&Bs[BUF][0] + udst0);                                          \
    gl16(bsrc + (size_t)(trow0 + 64) * 128 + ((tci0 ^ ((trow0 + 64) & 7)) << 3), \
         (char*)&Bs[BUF][0] + udst1);                                          \
  }

  f32x4 acc[2][4];
#pragma unroll
  for (int mt = 0; mt < 2; ++mt)
#pragma unroll
    for (int nt = 0; nt < 4; ++nt) acc[mt][nt] = (f32x4)0.f;

  // --- issue-early residual loads: 16 x-values used only in the epilogue ---
  float rxv[2][4][4];
#pragma unroll
  for (int mt = 0; mt < 2; ++mt)
#pragma unroll
    for (int nt = 0; nt < 4; ++nt) {
      const int px = px0w + nt * 16 + lm;
#pragma unroll
      for (int r = 0; r < 4; ++r) {
        const int oc = oc0w + mt * 16 + lh * 4 + r;
        rxv[mt][nt][r] =
            xin[((size_t)(b * C_ + oc)) * HW_ + (size_t)y * W_ + px];
      }
    }
  // keep the loads issued here (prevent sinking past the loop)
#pragma unroll
  for (int mt = 0; mt < 2; ++mt)
#pragma unroll
    for (int nt = 0; nt < 4; ++nt)
#pragma unroll
      for (int r = 0; r < 4; ++r)
        asm volatile("" :: "v"(rxv[mt][nt][r]));

  STAGE(0, 0);
  __syncthreads();   // drains vmcnt -> buf0 ready

  int cur = 0;
#pragma unroll 1
  for (int s = 0; s < 18; ++s) {
    if (s + 1 < 18) STAGE(cur ^ 1, s + 1);   // async prefetch under MFMAs

    const char* Ab = (const char*)&As[cur][0];
    const char* Bb = (const char*)&Bs[cur][0];
#pragma unroll
    for (int ki = 0; ki < 2; ++ki) {
      short8 af[2], bfr[4];
#pragma unroll
      for (int mt = 0; mt < 2; ++mt) {
        const int oc = oc0w + mt * 16 + lm;
        af[mt] = *(const short8*)(Ab + oc * 128 + (((ki * 4 + lh) ^ (oc & 7)) << 4));
      }
#pragma unroll
      for (int nt = 0; nt < 4; ++nt) {
        const int px = px0w + nt * 16 + lm;
        bfr[nt] = *(const short8*)(Bb + px * 128 + (((ki * 4 + lh) ^ (px & 7)) << 4));
      }
#pragma unroll
      for (int mt = 0; mt < 2; ++mt) {
        acc[mt][0] = mfma16(af[mt], bfr[0], acc[mt][0]);
        acc[mt][1] = mfma16(af[mt], bfr[1], acc[mt][1]);
        acc[mt][2] = mfma16(af[mt], bfr[2], acc[mt][2]);
        acc[mt][3] = mfma16(af[mt], bfr[3], acc[mt][3]);
      }
    }
    __syncthreads();   // waits prefetch (vmcnt) + protects buf overwrite
    cur ^= 1;
  }
#undef STAGE

  // epilogue: per-oc constant terms (reuse As as f32 scratch)
  float* sm = (float*)&As[0][0];   // [3][128]: add, left, right
  if (tid < 128) {
    const float* Tk = ws + OFF_T + (size_t)(b * 128 + tid) * 9;
    float s = Tk[3] + Tk[4] + Tk[5], sl = Tk[3], sr = Tk[5];
    if (y >= 1)   { s += Tk[0] + Tk[1] + Tk[2]; sl += Tk[0]; sr += Tk[2]; }
    if (y <= 126) { s += Tk[6] + Tk[7] + Tk[8]; sl += Tk[6]; sr += Tk[8]; }
    sm[tid] = s + b_f[tid]; sm[128 + tid] = sl; sm[256 + tid] = sr;
  }
  __syncthreads();

#pragma unroll
  for (int mt = 0; mt < 2; ++mt)
#pragma unroll
    for (int nt = 0; nt < 4; ++nt) {
      const int px = px0w + nt * 16 + lm;
#pragma unroll
      for (int r = 0; r < 4; ++r) {
        const int oc = oc0w + mt * 16 + lh * 4 + r;
        float add = sm[oc];
        if (px == 0)   add -= sm[128 + oc];
        if (px == 127) add -= sm[256 + oc];
        const float z = acc[mt][nt][r] + add;
        const size_t base = ((size_t)(b * C_ + oc)) * HW_ + (size_t)y * W_ + px;
        out[base] = rxv[mt][nt][r] + (z >= 0.f ? z : 0.2f * z);
      }
    }
}

// K4 fallback (R2 version): used when ws_size can't hold T2.
__global__ __launch_bounds__(512, 4) void k_conv_fb(const float* __restrict__ xin,
                                                    const float* __restrict__ to,
                                                    const float* __restrict__ b_f,
                                                    const float* __restrict__ ws,
                                                    float* __restrict__ out) {
  const int bid = blockIdx.x;
  const int nb  = (bid & 7) * 128 + (bid >> 3);
  const int b   = nb >> 7;
  const int y   = nb & 127;
  const int tid = threadIdx.x;

  __shared__ f32x4 ldsbuf[3120];
  char* lp = (char*)ldsbuf;

  f32x4 acc[4][2];
#pragma unroll
  for (int mt = 0; mt < 4; ++mt)
#pragma unroll
    for (int nt = 0; nt < 2; ++nt) acc[mt][nt] = (f32x4)0.f;

  const float* tob = to + (size_t)b * C_ * HW_;
  const unsigned short* wb16 =
      (const unsigned short*)(ws + OFF_WEFF) + (size_t)b * 9 * 128 * 128;

  const int l = tid & 63, wv = tid >> 6;
  const int ocb0 = (wv & 1) * 64, pxb0 = (wv >> 1) * 32;
  const int lm = l & 15, lh = l >> 4;

  for (int cb = 0; cb < 128; cb += 64) {
    __syncthreads();
    {
      const int xg = tid & 31, cq = (tid >> 5) & 15;
      const int cbase = cb + cq * 4;
#pragma unroll
      for (int row = 0; row < 3; ++row) {
        const int y_in = y + row - 1;
        const bool yok = ((unsigned)y_in < 128u);
        const float* src = tob + (size_t)cbase * HW_ + (size_t)y_in * W_;
#pragma unroll
        for (int xb = 0; xb < 5; ++xb) {
          const int xi = xb * 32 + xg;
          if (xi < 130) {
            const int x_in = xi - 1;
            const bool ok = yok && ((unsigned)x_in < 128u);
            float f0 = 0.f, f1 = 0.f, f2 = 0.f, f3 = 0.f;
            if (ok) {
              f0 = src[x_in];
              f1 = src[HW_ + x_in];
              f2 = src[2 * HW_ + x_in];
              f3 = src[3 * HW_ + x_in];
            }
            ushort4 pk;
            pk.x = f2bf(f0); pk.y = f2bf(f1); pk.z = f2bf(f2); pk.w = f2bf(f3);
            const int boff = (row * 130 + xi) * 128 + ((cq * 8) ^ ((xi & 7) << 4));
            *(ushort4*)(lp + boff) = pk;
          }
        }
      }
    }
    __syncthreads();

    for (int tap = 0; tap < 9; ++tap) {
      const int dy = tap / 3, dx = tap - dy * 3;
#pragma unroll
      for (int ks = 0; ks < 2; ++ks) {
        short8 bfr[2];
#pragma unroll
        for (int nt = 0; nt < 2; ++nt) {
          const int xi = pxb0 + nt * 16 + lm + dx;
          const int boff = (dy * 130 + xi) * 128 + ((ks * 64 + lh * 16) ^ ((xi & 7) << 4));
          bfr[nt] = *(const short8*)(lp + boff);
        }
        const int cin = cb + ks * 32 + lh * 8;
#pragma unroll
        for (int mt = 0; mt < 4; ++mt) {
          const int oc = ocb0 + mt * 16 + lm;
          const short8 af = *(const short8*)(wb16 + ((size_t)tap * 128 + oc) * 128 + cin);
          acc[mt][0] = mfma16(af, bfr[0], acc[mt][0]);
          acc[mt][1] = mfma16(af, bfr[1], acc[mt][1]);
        }
      }
    }
  }

  __syncthreads();
  float* sAdd = (float*)ldsbuf;
  float* sLft = sAdd + 128;
  float* sRgt = sAdd + 256;
  if (tid < 128) {
    const float* Tk = ws + OFF_T + (size_t)(b * 128 + tid) * 9;
    float s = Tk[3] + Tk[4] + Tk[5], sl = Tk[3], sr = Tk[5];
    if (y >= 1)   { s += Tk[0] + Tk[1] + Tk[2]; sl += Tk[0]; sr += Tk[2]; }
    if (y <= 126) { s += Tk[6] + Tk[7] + Tk[8]; sl += Tk[6]; sr += Tk[8]; }
    sAdd[tid] = s + b_f[tid]; sLft[tid] = sl; sRgt[tid] = sr;
  }
  __syncthreads();

#pragma unroll
  for (int mt = 0; mt < 4; ++mt)
#pragma unroll
    for (int nt = 0; nt < 2; ++nt) {
      const int px = pxb0 + nt * 16 + lm;
#pragma unroll
      for (int r = 0; r < 4; ++r) {
        const int oc = ocb0 + mt * 16 + lh * 4 + r;
        float add = sAdd[oc];
        if (px == 0)   add -= sLft[oc];
        if (px == 127) add -= sRgt[oc];
        const float z = acc[mt][nt][r] + add;
        const size_t base = ((size_t)(b * C_ + oc)) * HW_ + (size_t)y * W_ + px;
        const float rx = xin[base];
        out[base] = rx + (z >= 0.f ? z : 0.2f * z);
      }
    }
}

extern "C" void kernel_launch(void* const* d_in, const int* in_sizes, int n_in,
                              void* d_out, int out_size, void* d_ws, size_t ws_size,
                              hipStream_t stream) {
  (void)in_sizes; (void)n_in; (void)out_size;
  const float* x    = (const float*)d_in[0];
  const float* to   = (const float*)d_in[1];
  const float* t    = (const float*)d_in[2];
  const float* w_r1 = (const float*)d_in[3];
  const float* b_r1 = (const float*)d_in[4];
  const float* w_r2 = (const float*)d_in[5];
  const float* b_r2 = (const float*)d_in[6];
  const float* w_r3 = (const float*)d_in[7];
  const float* b_r3 = (const float*)d_in[8];
  const float* w_t1 = (const float*)d_in[9];
  const float* b_t1 = (const float*)d_in[10];
  const float* w_t2 = (const float*)d_in[11];
  const float* b_t2 = (const float*)d_in[12];
  const float* w_t3 = (const float*)d_in[13];
  const float* b_t3 = (const float*)d_in[14];
  const float* w_f  = (const float*)d_in[15];
  const float* b_f  = (const float*)d_in[16];
  float* ws  = (float*)d_ws;
  float* out = (float*)d_out;
  unsigned short* t2 = (unsigned short*)(ws + OFF_T2F);
  const bool fast = (ws_size >= WS_NEED);

  if (fast) {
    k_pre<<<3088, 256, 0, stream>>>(x, to, ws, t2);
  } else {
    k_pre<<<1024, 256, 0, stream>>>(x, to, ws, t2);  // gram blocks only
  }
  k_attn<<<8, 256, 0, stream>>>(t, w_r1, b_r1, w_r2, b_r2, w_r3, b_r3,
                                w_t1, b_t1, w_t2, b_t2, w_t3, b_t3, ws);
  k_weff<<<1024, 128, 0, stream>>>(w_f, ws);
  if (fast) k_conv<<<1024, 512, 0, stream>>>(x, b_f, ws, t2, out);
  else      k_conv_fb<<<1024, 512, 0, stream>>>(x, to, b_f, ws, out);
}